// Round 2
// baseline (270.294 us; speedup 1.0000x reference)
//
#include <hip/hip_runtime.h>
#include <math.h>

#define NN 4096   // nodes
#define LOG2E 1.44269504088896340736f

using f32x2  = __attribute__((ext_vector_type(2))) float;
using f32x4  = __attribute__((ext_vector_type(4))) float;
using bf16x4 = __attribute__((ext_vector_type(4))) __bf16;
using bf16x8 = __attribute__((ext_vector_type(8))) __bf16;

// exp2 in one v_exp_f32 (inputs are pre-scaled by log2e)
#if __has_builtin(__builtin_amdgcn_exp2f)
#define EXP2(x) __builtin_amdgcn_exp2f(x)
#else
#define EXP2(x) __expf((x) * 0.6931471805599453f)
#endif

// lgkm-only barrier: does NOT drain vmcnt, so global_load_lds prefetch stays in
// flight across it (plain __syncthreads would emit s_waitcnt vmcnt(0)).
__device__ __forceinline__ void barrier_lgkm() {
    asm volatile("s_waitcnt lgkmcnt(0)\ns_barrier" ::: "memory");
}

// ---------------- async global->LDS staging (16B, XOR-swizzled chunks) ----------------
// Row f of 64 bf16 = 8 chunks of 8; LDS slot s of row f holds global chunk s^(f&7).
template<int FH>
__device__ __forceinline__ void stage_tile(const __bf16* __restrict__ hgp,
                                           __bf16* dst, int tid) {
#pragma unroll
    for (int it = 0; it < FH / 32; it++) {
        int c = tid + it * 256;
        int f = c >> 3, sl = c & 7;
        int g = sl ^ (f & 7);
        __builtin_amdgcn_global_load_lds(
            (const __attribute__((address_space(1))) void*)(hgp + (size_t)f * NN + g * 8),
            (__attribute__((address_space(3))) void*)(dst + (size_t)c * 8), 16, 0, 0);
    }
}

__device__ __forceinline__ void stage_g(const __bf16* __restrict__ base, int ldk,
                                        __bf16* dst, int tid) {
#pragma unroll
    for (int it = 0; it < 2; it++) {
        int c = tid + it * 256;
        int f = c >> 3, sl = c & 7;
        int g = sl ^ (f & 7);
        __builtin_amdgcn_global_load_lds(
            (const __attribute__((address_space(1))) void*)(base + (size_t)f * ldk + g * 8),
            (__attribute__((address_space(3))) void*)(dst + (size_t)c * 8), 16, 0, 0);
    }
}

// ---------------- adjacency -> bitmask ----------------
__global__ void pack_adj_kernel(const int* __restrict__ adj,
                                unsigned long long* __restrict__ bits) {
    int gw = (blockIdx.x * blockDim.x + threadIdx.x) >> 6;
    int lane = threadIdx.x & 63;
    int v = adj[(size_t)gw * 64 + lane];
    unsigned long long m = __ballot(v > 0);
    if (lane == 0) bits[gw] = m;
}

// ---------------- prepack: W_h -> Bt1[n=512][k=512] bf16, W_o -> Bt2[n=64][k=512] ----
__global__ void prepack_kernel(const float* __restrict__ W_h, const float* __restrict__ b_h,
                               const float* __restrict__ W_o,
                               __bf16* __restrict__ Bt1, float* __restrict__ biasp,
                               __bf16* __restrict__ Bt2) {
    int idx = blockIdx.x * 256 + threadIdx.x;   // 512*512
    {
        int n = idx >> 9, k = idx & 511;
        int h = n >> 7, f = n & 127;
        Bt1[idx] = (__bf16)W_h[(size_t)h * 512 * 128 + k * 128 + f];
    }
    if (idx < 64 * 512) {
        int n = idx >> 9, k = idx & 511;
        Bt2[idx] = (__bf16)W_o[k * 64 + n];
    }
    if (idx < 512) biasp[idx] = b_h[idx];
}

// ---------------- fp32 -> bf16 cast ----------------
__global__ void cast_bf16_kernel(const float* __restrict__ src, __bf16* __restrict__ dst) {
    int i = blockIdx.x * 256 + threadIdx.x;
    f32x4 v = *(const f32x4*)(src + (size_t)i * 4);
    bf16x4 o;
#pragma unroll
    for (int q = 0; q < 4; q++) o[q] = (__bf16)v[q];
    *(bf16x4*)(dst + (size_t)i * 4) = o;
}

// ---------------- fused bf16 MFMA GEMM ----------------
// Ht[col][row] = bf16( (A @ Bt^T)[row][col] + bias[col] )   (transposed store)
// s1[head][row] += sum_col h*a1[col]*LOG2E, s2 likewise (pre-scaled for exp2;
// lrelu is positively homogeneous so the scale commutes through it exactly).
__global__ __launch_bounds__(256) void gemm_fused_kernel(
    const __bf16* __restrict__ A, const __bf16* __restrict__ Bt,
    const float* __restrict__ bias,
    const float* __restrict__ a1, const float* __restrict__ a2,
    __bf16* __restrict__ Ht, float* __restrict__ s1, float* __restrict__ s2,
    int M, int N, int K)
{
    __shared__ __attribute__((aligned(16))) __bf16 As[2][64 * 64];
    __shared__ __attribute__((aligned(16))) __bf16 Bs[2][64 * 64];
    const int tid = threadIdx.x, w = tid >> 6, l = tid & 63, o = l >> 4, rl = l & 15;
    const int bm = blockIdx.y * 64, bn = blockIdx.x * 64;
    f32x4 acc[4] = {};
    stage_g(A + (size_t)bm * K, K, &As[0][0], tid);
    stage_g(Bt + (size_t)bn * K, K, &Bs[0][0], tid);
    const int KB = K / 64;
    for (int kb = 0; kb < KB; kb++) {
        int b = kb & 1;
        __syncthreads();
        if (kb + 1 < KB) {
            stage_g(A + (size_t)bm * K + (kb + 1) * 64, K, &As[b ^ 1][0], tid);
            stage_g(Bt + (size_t)bn * K + (kb + 1) * 64, K, &Bs[b ^ 1][0], tid);
        }
#pragma unroll
        for (int kt = 0; kt < 2; kt++) {
            int ra = w * 16 + rl;
            int cg = kt * 4 + o;
            bf16x8 af = *(const bf16x8*)(&As[b][(ra * 8 + (cg ^ (ra & 7))) * 8]);
#pragma unroll
            for (int nt = 0; nt < 4; nt++) {
                int rb = nt * 16 + rl;
                bf16x8 bfr = *(const bf16x8*)(&Bs[b][(rb * 8 + (cg ^ (rb & 7))) * 8]);
                acc[nt] = __builtin_amdgcn_mfma_f32_16x16x32_bf16(af, bfr, acc[nt], 0, 0, 0);
            }
        }
    }
    // epilogue: bias, transposed bf16 store, s1/s2 row-dot partials
    const int head = bn >> 7;
    const int row_base = bm + w * 16 + o * 4;
    float p1[4] = {0.f, 0.f, 0.f, 0.f}, p2[4] = {0.f, 0.f, 0.f, 0.f};
#pragma unroll
    for (int nt = 0; nt < 4; nt++) {
        int col = bn + nt * 16 + rl;
        float bv = bias[col];
        float a1v = a1[col] * LOG2E, a2v = a2[col] * LOG2E;
        bf16x4 hv;
#pragma unroll
        for (int r4 = 0; r4 < 4; r4++) {
            float h = acc[nt][r4] + bv;
            hv[r4] = (__bf16)h;
            p1[r4] += h * a1v;
            p2[r4] += h * a2v;
        }
        *(bf16x4*)(Ht + (size_t)col * M + row_base) = hv;
    }
#pragma unroll
    for (int r4 = 0; r4 < 4; r4++)
#pragma unroll
        for (int off = 1; off < 16; off <<= 1) {
            p1[r4] += __shfl_xor(p1[r4], off, 64);
            p2[r4] += __shfl_xor(p2[r4], off, 64);
        }
    if (rl == 0)
#pragma unroll
        for (int r4 = 0; r4 < 4; r4++) {
            atomicAdd(&s1[(size_t)head * M + row_base + r4], p1[r4]);
            atomicAdd(&s2[(size_t)head * M + row_base + r4], p2[r4]);
        }
}

// ---------------- global max of s2 per head ----------------
__global__ void smax_kernel(const float* __restrict__ s2, float* __restrict__ s2max) {
    const float* p = s2 + (size_t)blockIdx.x * NN;
    int t = threadIdx.x;
    float m = -INFINITY;
    for (int i = t; i < NN; i += 256) m = fmaxf(m, p[i]);
#pragma unroll
    for (int off = 1; off < 64; off <<= 1) m = fmaxf(m, __shfl_xor(m, off, 64));
    __shared__ float red[4];
    if ((t & 63) == 0) red[t >> 6] = m;
    __syncthreads();
    if (t == 0) s2max[blockIdx.x] = fmaxf(fmaxf(red[0], red[1]), fmaxf(red[2], red[3]));
}

// ---------------- MFMA attention, fragment-reuse, j-split partials ----------------
// 64-row blocks, 4 waves. Wave w produces P A-frags for rows [w*16, w*16+16)
// and consumes n-tiles [w*NTW*16, (w+1)*NTW*16) for ALL 4 m-tiles.
// Round-2 changes vs the 228 µs version (phase-lock + latency diagnosis):
//  * RING STAGGER: each block starts its j-tile ring at blockIdx.x & (NJT-1).
//    Co-resident blocks were phase-locked (all produce together, all MFMA
//    together -> no pipe overlap). Stagger de-correlates them.
//  * T14 SPLIT: produce = pload (adj/s2 global loads) + pmath (VALU). pload
//    for tile jl+2 is issued before the MFMA cluster of jl, consumed one full
//    iteration later -> L2 latency (~200-400 cy) fully hidden.
//  * T5: s_setprio(1) around the MFMA cluster (pays off once de-phased).
//  * VALU cuts: mrow folded into u0/v0 (add+fma+max per elem), lacc cross-lane
//    reduce deferred to epilogue (removes 4 ds_bpermute + lgkm waits per iter).
template<int FH, int JSPLIT>
__global__ __launch_bounds__(256, 4) void attn_kernel(
    const __bf16* __restrict__ Htg,               // [heads*FH][NN]
    const unsigned long long* __restrict__ adj_bits,
    const float* __restrict__ s1_all, const float* __restrict__ s2_all,
    const float* __restrict__ s2max_all, const float* __restrict__ ab_all,
    __bf16* __restrict__ accp,                    // [JSPLIT][NN][ldo]
    float* __restrict__ lg,                       // [heads*JSPLIT][NN]
    int ldo)
{
    constexpr int NJT = NN / 64 / JSPLIT;
    constexpr int NTW = FH / 64;                  // n-tiles per wave (128->2, 64->1)
    const int head = blockIdx.y;
    const int js   = blockIdx.z;
    const int row0 = blockIdx.x * 64;
    const int jt0  = js * NJT;
    const int tid = threadIdx.x;
    const int w = tid >> 6, l = tid & 63, o = l >> 4, rl = l & 15;
    const int myrow = row0 + w * 16 + rl;         // producer row (mt = w)
    const int off = blockIdx.x & (NJT - 1);       // ring start (de-phase blocks)

    __shared__ __attribute__((aligned(16))) __bf16 hbuf[2][FH * 64];
    __shared__ __attribute__((aligned(16))) __bf16 plds[8 * 64 * 8];   // [mt*2+kt][lane]*8

    const float* s2 = s2_all + (size_t)head * NN;
    const __bf16* hg = Htg + (size_t)head * FH * NN;
    // s1/s2 already carry the LOG2E scale from the GEMM epilogue; ab scaled here.
    const float s1r = s1_all[(size_t)head * NN + myrow] + ab_all[head] * LOG2E;
    float mrow; { float x = s1r + s2max_all[head]; mrow = fmaxf(x, 0.2f * x); }
    const float u0 = s1r - mrow;                  // e-mrow = max(s+u0, fma(.2,s,v0))
    const float v0 = fmaf(0.2f, s1r, -mrow);
    float lacc = 0.f;                             // per-lane partial; reduced at end
    f32x4 acc[4][NTW] = {};

    auto ring = [&](int i) { return jt0 + ((i + off) & (NJT - 1)); };

    struct PLoad { unsigned long long aw; f32x4 sa[2]; f32x4 sb[2]; };
    auto pload = [&](int jt) {
        PLoad L;
        L.aw = adj_bits[(size_t)myrow * 64 + jt];
#pragma unroll
        for (int kt = 0; kt < 2; kt++) {
            const float* sp = s2 + jt * 64 + kt * 32 + o * 8;
            L.sa[kt] = *(const f32x4*)(sp);
            L.sb[kt] = *(const f32x4*)(sp + 4);
        }
        return L;
    };
    auto pmath = [&](const PLoad& L, bf16x8* fr) {
#pragma unroll
        for (int kt = 0; kt < 2; kt++) {
            unsigned int mbyte = (unsigned int)(L.aw >> ((kt * 4 + o) * 8)) & 0xFFu;
            float ps = 0.f;
#pragma unroll
            for (int q = 0; q < 8; q++) {
                float s = (q < 4) ? L.sa[kt][q] : L.sb[kt][q - 4];
                float u = s + u0;
                float v = fmaf(0.2f, s, v0);
                float t = fmaxf(u, v);
                t = ((mbyte >> q) & 1u) ? t : -1.0e20f;
                float p = EXP2(t);                // 2^t; masked -> exact 0
                fr[kt][q] = (__bf16)p;
                ps += p;
            }
            lacc += ps;
        }
    };

    stage_tile<FH>(hg + (size_t)ring(0) * 64, &hbuf[0][0], tid);
    PLoad L = pload(ring(0));
    bf16x8 freg[2];
    pmath(L, freg);                               // prologue: tile ring(0)
    if (NJT > 1) L = pload(ring(1));

    for (int jl = 0; jl < NJT; jl++) {
        const int b = jl & 1;
        // publish this tile's P fragments (plds free: previous B2 passed)
#pragma unroll
        for (int kt = 0; kt < 2; kt++)
            *(bf16x8*)(&plds[((w * 2 + kt) * 64 + l) * 8]) = freg[kt];
        __syncthreads();   // B1: plds visible; hbuf[b] DMA drained (vmcnt 0)
        if (jl + 1 < NJT)
            stage_tile<FH>(hg + (size_t)ring(jl + 1) * 64, &hbuf[b ^ 1][0], tid);
        // ---- B-frags once, reuse across all 4 m-tiles ----
        bf16x8 bfr[2][NTW];
#pragma unroll
        for (int kt = 0; kt < 2; kt++)
#pragma unroll
            for (int ntl = 0; ntl < NTW; ntl++) {
                int f = (w * NTW + ntl) * 16 + rl;
                int slot = (kt * 4 + o) ^ (rl & 7);
                bfr[kt][ntl] = *(const bf16x8*)(&hbuf[b][(f * 8 + slot) * 8]);
            }
        // ---- produce NEXT tile's fragments from regs loaded one iter ago ----
        bf16x8 fnext[2];
        if (jl + 1 < NJT) pmath(L, fnext);
        // ---- issue loads for tile jl+2 (consumed next iteration: full cover) ----
        if (jl + 2 < NJT) L = pload(ring(jl + 2));
        __builtin_amdgcn_s_setprio(1);
#pragma unroll
        for (int mt = 0; mt < 4; mt++)
#pragma unroll
            for (int kt = 0; kt < 2; kt++) {
                bf16x8 af = (mt == w) ? freg[kt]
                          : *(const bf16x8*)(&plds[((mt * 2 + kt) * 64 + l) * 8]);
#pragma unroll
                for (int ntl = 0; ntl < NTW; ntl++)
                    acc[mt][ntl] = __builtin_amdgcn_mfma_f32_16x16x32_bf16(
                        af, bfr[kt][ntl], acc[mt][ntl], 0, 0, 0);
            }
        __builtin_amdgcn_s_setprio(0);
        barrier_lgkm();    // B2: plds reads done; DMA prefetch stays in flight
        if (jl + 1 < NJT) { freg[0] = fnext[0]; freg[1] = fnext[1]; }
    }
    // ---- epilogue: cross-lane lacc reduce (deferred from loop) ----
    lacc += __shfl_xor(lacc, 16, 64);
    lacc += __shfl_xor(lacc, 32, 64);
    if (l < 16) lg[((size_t)head * JSPLIT + js) * NN + row0 + w * 16 + l] = lacc;
#pragma unroll
    for (int mt = 0; mt < 4; mt++)
#pragma unroll
        for (int ntl = 0; ntl < NTW; ntl++)
#pragma unroll
            for (int r4 = 0; r4 < 4; r4++) {
                int grow = row0 + mt * 16 + o * 4 + r4;
                int gcol = head * FH + (w * NTW + ntl) * 16 + rl;
                accp[((size_t)js * NN + grow) * ldo + gcol] = (__bf16)acc[mt][ntl][r4];
            }
}

// ---------------- combine layer-1 partials: normalize + elu -> bf16 [N][512] ----------------
__global__ void combine1_kernel(const __bf16* __restrict__ accp, const float* __restrict__ lg,
                                __bf16* __restrict__ outb) {
    int gid = blockIdx.x * 256 + threadIdx.x;        // N * 128
    int row = gid >> 7, c4 = (gid & 127) * 4;
    int head = c4 >> 7;
    float lsum = 0.f;
#pragma unroll
    for (int js = 0; js < 4; js++) lsum += lg[((size_t)head * 4 + js) * NN + row];
    float inv = lsum > 0.f ? 1.f / lsum : 0.f;
    float v[4] = {0.f, 0.f, 0.f, 0.f};
#pragma unroll
    for (int js = 0; js < 4; js++) {
        bf16x4 t = *(const bf16x4*)(accp + ((size_t)js * NN + row) * 512 + c4);
#pragma unroll
        for (int q = 0; q < 4; q++) v[q] += (float)t[q];
    }
    bf16x4 ob;
#pragma unroll
    for (int q = 0; q < 4; q++) {
        float x = v[q] * inv;
        x = x > 0.f ? x : __expf(x) - 1.f;
        ob[q] = (__bf16)x;
    }
    *(bf16x4*)(outb + (size_t)row * 512 + c4) = ob;
}

// ---------------- combine layer-2 partials + elu + log_softmax -> out ----------------
__global__ void combine2_kernel(const __bf16* __restrict__ accp, const float* __restrict__ lg,
                                float* __restrict__ out) {
    int row = (blockIdx.x * 256 + threadIdx.x) >> 6;
    int lane = threadIdx.x & 63;
    if (row >= NN) return;
    float lsum = 0.f, v = 0.f;
#pragma unroll
    for (int js = 0; js < 16; js++) {
        lsum += lg[(size_t)js * NN + row];
        v += (float)accp[((size_t)js * NN + row) * 64 + lane];
    }
    float inv = lsum > 0.f ? 1.f / lsum : 0.f;
    v *= inv;
    v = v > 0.f ? v : __expf(v) - 1.f;
    float m = v;
#pragma unroll
    for (int off = 1; off < 64; off <<= 1) m = fmaxf(m, __shfl_xor(m, off, 64));
    float ex = __expf(v - m);
    float s = ex;
#pragma unroll
    for (int off = 1; off < 64; off <<= 1) s += __shfl_xor(s, off, 64);
    out[(size_t)row * 64 + lane] = v - m - __logf(s);
}

extern "C" void kernel_launch(void* const* d_in, const int* in_sizes, int n_in,
                              void* d_out, int out_size, void* d_ws, size_t ws_size,
                              hipStream_t stream) {
    const float* X    = (const float*)d_in[0];
    const int*   adj  = (const int*)d_in[1];
    const float* W_h  = (const float*)d_in[2];
    const float* b_h  = (const float*)d_in[3];
    const float* a1_h = (const float*)d_in[4];
    const float* a2_h = (const float*)d_in[5];
    const float* ab_h = (const float*)d_in[6];
    const float* W_o  = (const float*)d_in[7];
    const float* b_o  = (const float*)d_in[8];
    const float* a1_o = (const float*)d_in[9];
    const float* a2_o = (const float*)d_in[10];
    const float* ab_o = (const float*)d_in[11];
    float* out = (float*)d_out;

    char* ws = (char*)d_ws;
    auto alloc = [&](size_t bytes) {
        char* p = ws; ws += (bytes + 255) & ~(size_t)255; return p;
    };
    unsigned long long* adj_bits = (unsigned long long*)alloc((size_t)NN * 64 * 8); // 2 MB
    __bf16* Bt1    = (__bf16*)alloc((size_t)512 * 512 * 2);     // 512 KB
    float*  biasp  = (float*)alloc(512 * 4);
    __bf16* Bt2    = (__bf16*)alloc((size_t)64 * 512 * 2);      // 64 KB
    __bf16* Xb     = (__bf16*)alloc((size_t)NN * 512 * 2);      // 4 MB
    float*  s1h    = (float*)alloc((size_t)4 * NN * 4);         // |-- contiguous,
    float*  s2h    = (float*)alloc((size_t)4 * NN * 4);         // |   one memset
    float*  s1o    = (float*)alloc((size_t)NN * 4);             // |   (160 KB)
    float*  s2o    = (float*)alloc((size_t)NN * 4);             // |
    float*  s2maxh = (float*)alloc(4 * 4);
    float*  s2maxo = (float*)alloc(4);
    __bf16* Htg    = (__bf16*)alloc((size_t)512 * NN * 2);      // 4 MB
    __bf16* accp1  = (__bf16*)alloc((size_t)4 * NN * 512 * 2);  // 16 MB
    float*  lg1    = (float*)alloc((size_t)16 * NN * 4);        // 256 KB
    __bf16* outhb  = (__bf16*)alloc((size_t)NN * 512 * 2);      // 4 MB
    __bf16* Ht2    = (__bf16*)alloc((size_t)64 * NN * 2);       // 512 KB
    __bf16* accp2  = (__bf16*)alloc((size_t)16 * NN * 64 * 2);  // 8 MB
    float*  lg2    = (float*)alloc((size_t)16 * NN * 4);        // 256 KB  (~40 MB)

    // 0. zero the atomic s1/s2 accumulators (contiguous block)
    hipMemsetAsync(s1h, 0, (size_t)(4 + 4 + 1 + 1) * NN * 4, stream);
    // 1. adjacency -> bitmasks (single read of the 67 MB int32 matrix)
    pack_adj_kernel<<<(NN * 64) / 4, 256, 0, stream>>>(adj, adj_bits);
    // 2. prepack weights (bf16, [n][k])
    prepack_kernel<<<1024, 256, 0, stream>>>(W_h, b_h, W_o, Bt1, biasp, Bt2);
    // 3. X -> bf16
    cast_bf16_kernel<<<(NN * 512 / 4) / 256, 256, 0, stream>>>(X, Xb);
    // 4. layer-1 GEMM fused: Htg (transposed bf16) + s1h/s2h atomics (LOG2E-scaled)
    gemm_fused_kernel<<<dim3(8, 64), 256, 0, stream>>>(
        Xb, Bt1, biasp, a1_h, a2_h, Htg, s1h, s2h, NN, 512, 512);
    // 5. per-head global s2 max
    smax_kernel<<<4, 256, 0, stream>>>(s2h, s2maxh);
    // 6. attention layer 1 partials (4 heads x 4 j-splits)
    attn_kernel<128, 4><<<dim3(NN / 64, 4, 4), 256, 0, stream>>>(
        Htg, adj_bits, s1h, s2h, s2maxh, ab_h, accp1, lg1, 512);
    // 7. combine -> elu -> bf16 concat features [N][512]
    combine1_kernel<<<(NN * 128) / 256, 256, 0, stream>>>(accp1, lg1, outhb);
    // 8. layer-2 GEMM fused: Ht2 (transposed bf16) + s1o/s2o atomics (LOG2E-scaled)
    gemm_fused_kernel<<<dim3(1, 64), 256, 0, stream>>>(
        outhb, Bt2, b_o, a1_o, a2_o, Ht2, s1o, s2o, NN, 64, 512);
    // 9. s2 max (output layer)
    smax_kernel<<<1, 256, 0, stream>>>(s2o, s2maxo);
    // 10. attention layer 2 partials (16 j-splits)
    attn_kernel<64, 16><<<dim3(NN / 64, 1, 16), 256, 0, stream>>>(
        Ht2, adj_bits, s1o, s2o, s2maxo, ab_o, accp2, lg2, 64);
    // 11. combine + elu + log_softmax -> out
    combine2_kernel<<<(NN * 64) / 256, 256, 0, stream>>>(accp2, lg2, out);
}

// Round 3
// 268.795 us; speedup vs baseline: 1.0056x; 1.0056x over previous
//
#include <hip/hip_runtime.h>
#include <math.h>

#define NN 4096   // nodes
#define LOG2E 1.44269504088896340736f

using f32x2  = __attribute__((ext_vector_type(2))) float;
using f32x4  = __attribute__((ext_vector_type(4))) float;
using bf16x4 = __attribute__((ext_vector_type(4))) __bf16;
using bf16x8 = __attribute__((ext_vector_type(8))) __bf16;

// exp2 in one v_exp_f32 (inputs are pre-scaled by log2e)
#if __has_builtin(__builtin_amdgcn_exp2f)
#define EXP2(x) __builtin_amdgcn_exp2f(x)
#else
#define EXP2(x) __expf((x) * 0.6931471805599453f)
#endif

// lgkm-only barrier: does NOT drain vmcnt, so global_load_lds prefetch stays in
// flight across it (plain __syncthreads would emit s_waitcnt vmcnt(0)).
__device__ __forceinline__ void barrier_lgkm() {
    asm volatile("s_waitcnt lgkmcnt(0)\ns_barrier" ::: "memory");
}

// ---------------- async global->LDS staging (16B, XOR-swizzled chunks) ----------------
// Row f of 64 bf16 = 8 chunks of 8; LDS slot s of row f holds global chunk s^(f&7).
template<int FH>
__device__ __forceinline__ void stage_tile(const __bf16* __restrict__ hgp,
                                           __bf16* dst, int tid) {
#pragma unroll
    for (int it = 0; it < FH / 32; it++) {
        int c = tid + it * 256;
        int f = c >> 3, sl = c & 7;
        int g = sl ^ (f & 7);
        __builtin_amdgcn_global_load_lds(
            (const __attribute__((address_space(1))) void*)(hgp + (size_t)f * NN + g * 8),
            (__attribute__((address_space(3))) void*)(dst + (size_t)c * 8), 16, 0, 0);
    }
}

__device__ __forceinline__ void stage_g(const __bf16* __restrict__ base, int ldk,
                                        __bf16* dst, int tid) {
#pragma unroll
    for (int it = 0; it < 2; it++) {
        int c = tid + it * 256;
        int f = c >> 3, sl = c & 7;
        int g = sl ^ (f & 7);
        __builtin_amdgcn_global_load_lds(
            (const __attribute__((address_space(1))) void*)(base + (size_t)f * ldk + g * 8),
            (__attribute__((address_space(3))) void*)(dst + (size_t)c * 8), 16, 0, 0);
    }
}

// ---------------- adjacency -> bitmask ----------------
__global__ void pack_adj_kernel(const int* __restrict__ adj,
                                unsigned long long* __restrict__ bits) {
    int gw = (blockIdx.x * blockDim.x + threadIdx.x) >> 6;
    int lane = threadIdx.x & 63;
    int v = adj[(size_t)gw * 64 + lane];
    unsigned long long m = __ballot(v > 0);
    if (lane == 0) bits[gw] = m;
}

// ---------------- prepack: W_h -> Bt1[n=512][k=512] bf16, W_o -> Bt2[n=64][k=512] ----
__global__ void prepack_kernel(const float* __restrict__ W_h, const float* __restrict__ b_h,
                               const float* __restrict__ W_o,
                               __bf16* __restrict__ Bt1, float* __restrict__ biasp,
                               __bf16* __restrict__ Bt2) {
    int idx = blockIdx.x * 256 + threadIdx.x;   // 512*512
    {
        int n = idx >> 9, k = idx & 511;
        int h = n >> 7, f = n & 127;
        Bt1[idx] = (__bf16)W_h[(size_t)h * 512 * 128 + k * 128 + f];
    }
    if (idx < 64 * 512) {
        int n = idx >> 9, k = idx & 511;
        Bt2[idx] = (__bf16)W_o[k * 64 + n];
    }
    if (idx < 512) biasp[idx] = b_h[idx];
}

// ---------------- fp32 -> bf16 cast ----------------
__global__ void cast_bf16_kernel(const float* __restrict__ src, __bf16* __restrict__ dst) {
    int i = blockIdx.x * 256 + threadIdx.x;
    f32x4 v = *(const f32x4*)(src + (size_t)i * 4);
    bf16x4 o;
#pragma unroll
    for (int q = 0; q < 4; q++) o[q] = (__bf16)v[q];
    *(bf16x4*)(dst + (size_t)i * 4) = o;
}

// ---------------- fused bf16 MFMA GEMM ----------------
// Ht[col][row] = bf16( (A @ Bt^T)[row][col] + bias[col] )   (transposed store)
// s1[head][row] += sum_col h*a1[col]*LOG2E, s2 likewise (pre-scaled for exp2;
// lrelu is positively homogeneous so the scale commutes through it exactly).
__global__ __launch_bounds__(256) void gemm_fused_kernel(
    const __bf16* __restrict__ A, const __bf16* __restrict__ Bt,
    const float* __restrict__ bias,
    const float* __restrict__ a1, const float* __restrict__ a2,
    __bf16* __restrict__ Ht, float* __restrict__ s1, float* __restrict__ s2,
    int M, int N, int K)
{
    __shared__ __attribute__((aligned(16))) __bf16 As[2][64 * 64];
    __shared__ __attribute__((aligned(16))) __bf16 Bs[2][64 * 64];
    const int tid = threadIdx.x, w = tid >> 6, l = tid & 63, o = l >> 4, rl = l & 15;
    const int bm = blockIdx.y * 64, bn = blockIdx.x * 64;
    f32x4 acc[4] = {};
    stage_g(A + (size_t)bm * K, K, &As[0][0], tid);
    stage_g(Bt + (size_t)bn * K, K, &Bs[0][0], tid);
    const int KB = K / 64;
    for (int kb = 0; kb < KB; kb++) {
        int b = kb & 1;
        __syncthreads();
        if (kb + 1 < KB) {
            stage_g(A + (size_t)bm * K + (kb + 1) * 64, K, &As[b ^ 1][0], tid);
            stage_g(Bt + (size_t)bn * K + (kb + 1) * 64, K, &Bs[b ^ 1][0], tid);
        }
#pragma unroll
        for (int kt = 0; kt < 2; kt++) {
            int ra = w * 16 + rl;
            int cg = kt * 4 + o;
            bf16x8 af = *(const bf16x8*)(&As[b][(ra * 8 + (cg ^ (ra & 7))) * 8]);
#pragma unroll
            for (int nt = 0; nt < 4; nt++) {
                int rb = nt * 16 + rl;
                bf16x8 bfr = *(const bf16x8*)(&Bs[b][(rb * 8 + (cg ^ (rb & 7))) * 8]);
                acc[nt] = __builtin_amdgcn_mfma_f32_16x16x32_bf16(af, bfr, acc[nt], 0, 0, 0);
            }
        }
    }
    // epilogue: bias, transposed bf16 store, s1/s2 row-dot partials
    const int head = bn >> 7;
    const int row_base = bm + w * 16 + o * 4;
    float p1[4] = {0.f, 0.f, 0.f, 0.f}, p2[4] = {0.f, 0.f, 0.f, 0.f};
#pragma unroll
    for (int nt = 0; nt < 4; nt++) {
        int col = bn + nt * 16 + rl;
        float bv = bias[col];
        float a1v = a1[col] * LOG2E, a2v = a2[col] * LOG2E;
        bf16x4 hv;
#pragma unroll
        for (int r4 = 0; r4 < 4; r4++) {
            float h = acc[nt][r4] + bv;
            hv[r4] = (__bf16)h;
            p1[r4] += h * a1v;
            p2[r4] += h * a2v;
        }
        *(bf16x4*)(Ht + (size_t)col * M + row_base) = hv;
    }
#pragma unroll
    for (int r4 = 0; r4 < 4; r4++)
#pragma unroll
        for (int off = 1; off < 16; off <<= 1) {
            p1[r4] += __shfl_xor(p1[r4], off, 64);
            p2[r4] += __shfl_xor(p2[r4], off, 64);
        }
    if (rl == 0)
#pragma unroll
        for (int r4 = 0; r4 < 4; r4++) {
            atomicAdd(&s1[(size_t)head * M + row_base + r4], p1[r4]);
            atomicAdd(&s2[(size_t)head * M + row_base + r4], p2[r4]);
        }
}

// ---------------- global max of s2 per head ----------------
__global__ void smax_kernel(const float* __restrict__ s2, float* __restrict__ s2max) {
    const float* p = s2 + (size_t)blockIdx.x * NN;
    int t = threadIdx.x;
    float m = -INFINITY;
    for (int i = t; i < NN; i += 256) m = fmaxf(m, p[i]);
#pragma unroll
    for (int off = 1; off < 64; off <<= 1) m = fmaxf(m, __shfl_xor(m, off, 64));
    __shared__ float red[4];
    if ((t & 63) == 0) red[t >> 6] = m;
    __syncthreads();
    if (t == 0) s2max[blockIdx.x] = fmaxf(fmaxf(red[0], red[1]), fmaxf(red[2], red[3]));
}

// ---------------- MFMA attention, fragment-reuse, j-split partials ----------------
// 64-row blocks, 4 waves. Wave w produces P A-frags for rows [w*16, w*16+16)
// and consumes n-tiles [w*NTW*16, (w+1)*NTW*16) for ALL 4 m-tiles.
// Round-3: LOCKSTEP tile order RESTORED (round-2's ring stagger destroyed L2
// read locality and caused 5x HBM write amplification on accp: FETCH 17.7->43MB,
// WRITE 16.6->86MB). Kept from round-2 (the good parts):
//  * T14 SPLIT: produce = pload (adj/s2 global loads) + pmath (VALU). pload
//    for tile jl+2 is issued before the MFMA cluster of jl, consumed one full
//    iteration later -> L2 latency fully hidden under MFMA+barriers+stage.
//  * T5: s_setprio(1) around the MFMA cluster.
//  * VALU cuts: exp2 pre-scaling, mrow folded into u0/v0, lacc cross-lane
//    reduce deferred to epilogue (removes 4 ds_bpermute + lgkm waits per iter).
template<int FH, int JSPLIT>
__global__ __launch_bounds__(256, 4) void attn_kernel(
    const __bf16* __restrict__ Htg,               // [heads*FH][NN]
    const unsigned long long* __restrict__ adj_bits,
    const float* __restrict__ s1_all, const float* __restrict__ s2_all,
    const float* __restrict__ s2max_all, const float* __restrict__ ab_all,
    __bf16* __restrict__ accp,                    // [JSPLIT][NN][ldo]
    float* __restrict__ lg,                       // [heads*JSPLIT][NN]
    int ldo)
{
    constexpr int NJT = NN / 64 / JSPLIT;
    constexpr int NTW = FH / 64;                  // n-tiles per wave (128->2, 64->1)
    const int head = blockIdx.y;
    const int js   = blockIdx.z;
    const int row0 = blockIdx.x * 64;
    const int jt0  = js * NJT;
    const int tid = threadIdx.x;
    const int w = tid >> 6, l = tid & 63, o = l >> 4, rl = l & 15;
    const int myrow = row0 + w * 16 + rl;         // producer row (mt = w)

    __shared__ __attribute__((aligned(16))) __bf16 hbuf[2][FH * 64];
    __shared__ __attribute__((aligned(16))) __bf16 plds[8 * 64 * 8];   // [mt*2+kt][lane]*8

    const float* s2 = s2_all + (size_t)head * NN;
    const __bf16* hg = Htg + (size_t)head * FH * NN;
    // s1/s2 already carry the LOG2E scale from the GEMM epilogue; ab scaled here.
    const float s1r = s1_all[(size_t)head * NN + myrow] + ab_all[head] * LOG2E;
    float mrow; { float x = s1r + s2max_all[head]; mrow = fmaxf(x, 0.2f * x); }
    const float u0 = s1r - mrow;                  // e-mrow = max(s+u0, fma(.2,s,v0))
    const float v0 = fmaf(0.2f, s1r, -mrow);
    float lacc = 0.f;                             // per-lane partial; reduced at end
    f32x4 acc[4][NTW] = {};

    struct PLoad { unsigned long long aw; f32x4 sa[2]; f32x4 sb[2]; };
    auto pload = [&](int jt) {
        PLoad L;
        L.aw = adj_bits[(size_t)myrow * 64 + jt];
#pragma unroll
        for (int kt = 0; kt < 2; kt++) {
            const float* sp = s2 + jt * 64 + kt * 32 + o * 8;
            L.sa[kt] = *(const f32x4*)(sp);
            L.sb[kt] = *(const f32x4*)(sp + 4);
        }
        return L;
    };
    auto pmath = [&](const PLoad& L, bf16x8* fr) {
#pragma unroll
        for (int kt = 0; kt < 2; kt++) {
            unsigned int mbyte = (unsigned int)(L.aw >> ((kt * 4 + o) * 8)) & 0xFFu;
            float ps = 0.f;
#pragma unroll
            for (int q = 0; q < 8; q++) {
                float s = (q < 4) ? L.sa[kt][q] : L.sb[kt][q - 4];
                float u = s + u0;
                float v = fmaf(0.2f, s, v0);
                float t = fmaxf(u, v);
                t = ((mbyte >> q) & 1u) ? t : -1.0e20f;
                float p = EXP2(t);                // 2^t; masked -> exact 0
                fr[kt][q] = (__bf16)p;
                ps += p;
            }
            lacc += ps;
        }
    };

    stage_tile<FH>(hg + (size_t)jt0 * 64, &hbuf[0][0], tid);
    PLoad L = pload(jt0);
    bf16x8 freg[2];
    pmath(L, freg);                               // prologue: tile 0
    if (NJT > 1) L = pload(jt0 + 1);

    for (int jl = 0; jl < NJT; jl++) {
        const int b = jl & 1;
        const int jt = jt0 + jl;
        // publish this tile's P fragments (plds free: previous B2 passed)
#pragma unroll
        for (int kt = 0; kt < 2; kt++)
            *(bf16x8*)(&plds[((w * 2 + kt) * 64 + l) * 8]) = freg[kt];
        __syncthreads();   // B1: plds visible; hbuf[b] DMA drained (vmcnt 0)
        if (jl + 1 < NJT)
            stage_tile<FH>(hg + (size_t)(jt + 1) * 64, &hbuf[b ^ 1][0], tid);
        // ---- B-frags once, reuse across all 4 m-tiles ----
        bf16x8 bfr[2][NTW];
#pragma unroll
        for (int kt = 0; kt < 2; kt++)
#pragma unroll
            for (int ntl = 0; ntl < NTW; ntl++) {
                int f = (w * NTW + ntl) * 16 + rl;
                int slot = (kt * 4 + o) ^ (rl & 7);
                bfr[kt][ntl] = *(const bf16x8*)(&hbuf[b][(f * 8 + slot) * 8]);
            }
        // ---- produce NEXT tile's fragments from regs loaded one iter ago ----
        bf16x8 fnext[2];
        if (jl + 1 < NJT) pmath(L, fnext);
        // ---- issue loads for tile jl+2 (consumed next iteration: full cover) ----
        if (jl + 2 < NJT) L = pload(jt + 2);
        __builtin_amdgcn_s_setprio(1);
#pragma unroll
        for (int mt = 0; mt < 4; mt++)
#pragma unroll
            for (int kt = 0; kt < 2; kt++) {
                bf16x8 af = (mt == w) ? freg[kt]
                          : *(const bf16x8*)(&plds[((mt * 2 + kt) * 64 + l) * 8]);
#pragma unroll
                for (int ntl = 0; ntl < NTW; ntl++)
                    acc[mt][ntl] = __builtin_amdgcn_mfma_f32_16x16x32_bf16(
                        af, bfr[kt][ntl], acc[mt][ntl], 0, 0, 0);
            }
        __builtin_amdgcn_s_setprio(0);
        barrier_lgkm();    // B2: plds reads done; DMA prefetch stays in flight
        if (jl + 1 < NJT) { freg[0] = fnext[0]; freg[1] = fnext[1]; }
    }
    // ---- epilogue: cross-lane lacc reduce (deferred from loop) ----
    lacc += __shfl_xor(lacc, 16, 64);
    lacc += __shfl_xor(lacc, 32, 64);
    if (l < 16) lg[((size_t)head * JSPLIT + js) * NN + row0 + w * 16 + l] = lacc;
#pragma unroll
    for (int mt = 0; mt < 4; mt++)
#pragma unroll
        for (int ntl = 0; ntl < NTW; ntl++)
#pragma unroll
            for (int r4 = 0; r4 < 4; r4++) {
                int grow = row0 + mt * 16 + o * 4 + r4;
                int gcol = head * FH + (w * NTW + ntl) * 16 + rl;
                accp[((size_t)js * NN + grow) * ldo + gcol] = (__bf16)acc[mt][ntl][r4];
            }
}

// ---------------- combine layer-1 partials: normalize + elu -> bf16 [N][512] ----------------
__global__ void combine1_kernel(const __bf16* __restrict__ accp, const float* __restrict__ lg,
                                __bf16* __restrict__ outb) {
    int gid = blockIdx.x * 256 + threadIdx.x;        // N * 128
    int row = gid >> 7, c4 = (gid & 127) * 4;
    int head = c4 >> 7;
    float lsum = 0.f;
#pragma unroll
    for (int js = 0; js < 4; js++) lsum += lg[((size_t)head * 4 + js) * NN + row];
    float inv = lsum > 0.f ? 1.f / lsum : 0.f;
    float v[4] = {0.f, 0.f, 0.f, 0.f};
#pragma unroll
    for (int js = 0; js < 4; js++) {
        bf16x4 t = *(const bf16x4*)(accp + ((size_t)js * NN + row) * 512 + c4);
#pragma unroll
        for (int q = 0; q < 4; q++) v[q] += (float)t[q];
    }
    bf16x4 ob;
#pragma unroll
    for (int q = 0; q < 4; q++) {
        float x = v[q] * inv;
        x = x > 0.f ? x : __expf(x) - 1.f;
        ob[q] = (__bf16)x;
    }
    *(bf16x4*)(outb + (size_t)row * 512 + c4) = ob;
}

// ---------------- combine layer-2 partials + elu + log_softmax -> out ----------------
__global__ void combine2_kernel(const __bf16* __restrict__ accp, const float* __restrict__ lg,
                                float* __restrict__ out) {
    int row = (blockIdx.x * 256 + threadIdx.x) >> 6;
    int lane = threadIdx.x & 63;
    if (row >= NN) return;
    float lsum = 0.f, v = 0.f;
#pragma unroll
    for (int js = 0; js < 16; js++) {
        lsum += lg[(size_t)js * NN + row];
        v += (float)accp[((size_t)js * NN + row) * 64 + lane];
    }
    float inv = lsum > 0.f ? 1.f / lsum : 0.f;
    v *= inv;
    v = v > 0.f ? v : __expf(v) - 1.f;
    float m = v;
#pragma unroll
    for (int off = 1; off < 64; off <<= 1) m = fmaxf(m, __shfl_xor(m, off, 64));
    float ex = __expf(v - m);
    float s = ex;
#pragma unroll
    for (int off = 1; off < 64; off <<= 1) s += __shfl_xor(s, off, 64);
    out[(size_t)row * 64 + lane] = v - m - __logf(s);
}

extern "C" void kernel_launch(void* const* d_in, const int* in_sizes, int n_in,
                              void* d_out, int out_size, void* d_ws, size_t ws_size,
                              hipStream_t stream) {
    const float* X    = (const float*)d_in[0];
    const int*   adj  = (const int*)d_in[1];
    const float* W_h  = (const float*)d_in[2];
    const float* b_h  = (const float*)d_in[3];
    const float* a1_h = (const float*)d_in[4];
    const float* a2_h = (const float*)d_in[5];
    const float* ab_h = (const float*)d_in[6];
    const float* W_o  = (const float*)d_in[7];
    const float* b_o  = (const float*)d_in[8];
    const float* a1_o = (const float*)d_in[9];
    const float* a2_o = (const float*)d_in[10];
    const float* ab_o = (const float*)d_in[11];
    float* out = (float*)d_out;

    char* ws = (char*)d_ws;
    auto alloc = [&](size_t bytes) {
        char* p = ws; ws += (bytes + 255) & ~(size_t)255; return p;
    };
    unsigned long long* adj_bits = (unsigned long long*)alloc((size_t)NN * 64 * 8); // 2 MB
    __bf16* Bt1    = (__bf16*)alloc((size_t)512 * 512 * 2);     // 512 KB
    float*  biasp  = (float*)alloc(512 * 4);
    __bf16* Bt2    = (__bf16*)alloc((size_t)64 * 512 * 2);      // 64 KB
    __bf16* Xb     = (__bf16*)alloc((size_t)NN * 512 * 2);      // 4 MB
    float*  s1h    = (float*)alloc((size_t)4 * NN * 4);         // |-- contiguous,
    float*  s2h    = (float*)alloc((size_t)4 * NN * 4);         // |   one memset
    float*  s1o    = (float*)alloc((size_t)NN * 4);             // |   (160 KB)
    float*  s2o    = (float*)alloc((size_t)NN * 4);             // |
    float*  s2maxh = (float*)alloc(4 * 4);
    float*  s2maxo = (float*)alloc(4);
    __bf16* Htg    = (__bf16*)alloc((size_t)512 * NN * 2);      // 4 MB
    __bf16* accp1  = (__bf16*)alloc((size_t)4 * NN * 512 * 2);  // 16 MB
    float*  lg1    = (float*)alloc((size_t)16 * NN * 4);        // 256 KB
    __bf16* outhb  = (__bf16*)alloc((size_t)NN * 512 * 2);      // 4 MB
    __bf16* Ht2    = (__bf16*)alloc((size_t)64 * NN * 2);       // 512 KB
    __bf16* accp2  = (__bf16*)alloc((size_t)16 * NN * 64 * 2);  // 8 MB
    float*  lg2    = (float*)alloc((size_t)16 * NN * 4);        // 256 KB  (~40 MB)

    // 0. zero the atomic s1/s2 accumulators (contiguous block)
    hipMemsetAsync(s1h, 0, (size_t)(4 + 4 + 1 + 1) * NN * 4, stream);
    // 1. adjacency -> bitmasks (single read of the 67 MB int32 matrix)
    pack_adj_kernel<<<(NN * 64) / 4, 256, 0, stream>>>(adj, adj_bits);
    // 2. prepack weights (bf16, [n][k])
    prepack_kernel<<<1024, 256, 0, stream>>>(W_h, b_h, W_o, Bt1, biasp, Bt2);
    // 3. X -> bf16
    cast_bf16_kernel<<<(NN * 512 / 4) / 256, 256, 0, stream>>>(X, Xb);
    // 4. layer-1 GEMM fused: Htg (transposed bf16) + s1h/s2h atomics (LOG2E-scaled)
    gemm_fused_kernel<<<dim3(8, 64), 256, 0, stream>>>(
        Xb, Bt1, biasp, a1_h, a2_h, Htg, s1h, s2h, NN, 512, 512);
    // 5. per-head global s2 max
    smax_kernel<<<4, 256, 0, stream>>>(s2h, s2maxh);
    // 6. attention layer 1 partials (4 heads x 4 j-splits)
    attn_kernel<128, 4><<<dim3(NN / 64, 4, 4), 256, 0, stream>>>(
        Htg, adj_bits, s1h, s2h, s2maxh, ab_h, accp1, lg1, 512);
    // 7. combine -> elu -> bf16 concat features [N][512]
    combine1_kernel<<<(NN * 128) / 256, 256, 0, stream>>>(accp1, lg1, outhb);
    // 8. layer-2 GEMM fused: Ht2 (transposed bf16) + s1o/s2o atomics (LOG2E-scaled)
    gemm_fused_kernel<<<dim3(1, 64), 256, 0, stream>>>(
        outhb, Bt2, b_o, a1_o, a2_o, Ht2, s1o, s2o, NN, 64, 512);
    // 9. s2 max (output layer)
    smax_kernel<<<1, 256, 0, stream>>>(s2o, s2maxo);
    // 10. attention layer 2 partials (16 j-splits)
    attn_kernel<64, 16><<<dim3(NN / 64, 1, 16), 256, 0, stream>>>(
        Ht2, adj_bits, s1o, s2o, s2maxo, ab_o, accp2, lg2, 64);
    // 11. combine + elu + log_softmax -> out
    combine2_kernel<<<(NN * 64) / 256, 256, 0, stream>>>(accp2, lg2, out);
}

// Round 4
// 226.968 us; speedup vs baseline: 1.1909x; 1.1843x over previous
//
#include <hip/hip_runtime.h>
#include <math.h>

#define NN 4096   // nodes
#define LOG2E 1.44269504088896340736f

using f32x2  = __attribute__((ext_vector_type(2))) float;
using f32x4  = __attribute__((ext_vector_type(4))) float;
using bf16x4 = __attribute__((ext_vector_type(4))) __bf16;
using bf16x8 = __attribute__((ext_vector_type(8))) __bf16;

// exp2 in one v_exp_f32 (inputs are pre-scaled by log2e)
#if __has_builtin(__builtin_amdgcn_exp2f)
#define EXP2(x) __builtin_amdgcn_exp2f(x)
#else
#define EXP2(x) __expf((x) * 0.6931471805599453f)
#endif

// lgkm-only barrier: does NOT drain vmcnt, so global_load_lds prefetch stays in
// flight across it (plain __syncthreads would emit s_waitcnt vmcnt(0)).
__device__ __forceinline__ void barrier_lgkm() {
    asm volatile("s_waitcnt lgkmcnt(0)\ns_barrier" ::: "memory");
}

// ---------------- async global->LDS staging (16B, XOR-swizzled chunks) ----------------
// Row f of 64 bf16 = 8 chunks of 8; LDS slot s of row f holds global chunk s^(f&7).
template<int FH>
__device__ __forceinline__ void stage_tile(const __bf16* __restrict__ hgp,
                                           __bf16* dst, int tid) {
#pragma unroll
    for (int it = 0; it < FH / 32; it++) {
        int c = tid + it * 256;
        int f = c >> 3, sl = c & 7;
        int g = sl ^ (f & 7);
        __builtin_amdgcn_global_load_lds(
            (const __attribute__((address_space(1))) void*)(hgp + (size_t)f * NN + g * 8),
            (__attribute__((address_space(3))) void*)(dst + (size_t)c * 8), 16, 0, 0);
    }
}

__device__ __forceinline__ void stage_g(const __bf16* __restrict__ base, int ldk,
                                        __bf16* dst, int tid) {
#pragma unroll
    for (int it = 0; it < 2; it++) {
        int c = tid + it * 256;
        int f = c >> 3, sl = c & 7;
        int g = sl ^ (f & 7);
        __builtin_amdgcn_global_load_lds(
            (const __attribute__((address_space(1))) void*)(base + (size_t)f * ldk + g * 8),
            (__attribute__((address_space(3))) void*)(dst + (size_t)c * 8), 16, 0, 0);
    }
}

// ---------------- adjacency -> bitmask ----------------
__global__ void pack_adj_kernel(const int* __restrict__ adj,
                                unsigned long long* __restrict__ bits) {
    int gw = (blockIdx.x * blockDim.x + threadIdx.x) >> 6;
    int lane = threadIdx.x & 63;
    int v = adj[(size_t)gw * 64 + lane];
    unsigned long long m = __ballot(v > 0);
    if (lane == 0) bits[gw] = m;
}

// ---------------- prepack: W_h -> Bt1[n=512][k=512] bf16, W_o -> Bt2[n=64][k=512] ----
__global__ void prepack_kernel(const float* __restrict__ W_h, const float* __restrict__ b_h,
                               const float* __restrict__ W_o,
                               __bf16* __restrict__ Bt1, float* __restrict__ biasp,
                               __bf16* __restrict__ Bt2) {
    int idx = blockIdx.x * 256 + threadIdx.x;   // 512*512
    {
        int n = idx >> 9, k = idx & 511;
        int h = n >> 7, f = n & 127;
        Bt1[idx] = (__bf16)W_h[(size_t)h * 512 * 128 + k * 128 + f];
    }
    if (idx < 64 * 512) {
        int n = idx >> 9, k = idx & 511;
        Bt2[idx] = (__bf16)W_o[k * 64 + n];
    }
    if (idx < 512) biasp[idx] = b_h[idx];
}

// ---------------- fp32 -> bf16 cast ----------------
__global__ void cast_bf16_kernel(const float* __restrict__ src, __bf16* __restrict__ dst) {
    int i = blockIdx.x * 256 + threadIdx.x;
    f32x4 v = *(const f32x4*)(src + (size_t)i * 4);
    bf16x4 o;
#pragma unroll
    for (int q = 0; q < 4; q++) o[q] = (__bf16)v[q];
    *(bf16x4*)(dst + (size_t)i * 4) = o;
}

// ---------------- fused bf16 MFMA GEMM ----------------
// Ht[col][row] = bf16( (A @ Bt^T)[row][col] + bias[col] )   (transposed store)
// s1[head][row] += sum_col h*a1[col]*LOG2E, s2 likewise (pre-scaled for exp2;
// lrelu is positively homogeneous so the scale commutes through it exactly).
__global__ __launch_bounds__(256) void gemm_fused_kernel(
    const __bf16* __restrict__ A, const __bf16* __restrict__ Bt,
    const float* __restrict__ bias,
    const float* __restrict__ a1, const float* __restrict__ a2,
    __bf16* __restrict__ Ht, float* __restrict__ s1, float* __restrict__ s2,
    int M, int N, int K)
{
    __shared__ __attribute__((aligned(16))) __bf16 As[2][64 * 64];
    __shared__ __attribute__((aligned(16))) __bf16 Bs[2][64 * 64];
    const int tid = threadIdx.x, w = tid >> 6, l = tid & 63, o = l >> 4, rl = l & 15;
    const int bm = blockIdx.y * 64, bn = blockIdx.x * 64;
    f32x4 acc[4] = {};
    stage_g(A + (size_t)bm * K, K, &As[0][0], tid);
    stage_g(Bt + (size_t)bn * K, K, &Bs[0][0], tid);
    const int KB = K / 64;
    for (int kb = 0; kb < KB; kb++) {
        int b = kb & 1;
        __syncthreads();
        if (kb + 1 < KB) {
            stage_g(A + (size_t)bm * K + (kb + 1) * 64, K, &As[b ^ 1][0], tid);
            stage_g(Bt + (size_t)bn * K + (kb + 1) * 64, K, &Bs[b ^ 1][0], tid);
        }
#pragma unroll
        for (int kt = 0; kt < 2; kt++) {
            int ra = w * 16 + rl;
            int cg = kt * 4 + o;
            bf16x8 af = *(const bf16x8*)(&As[b][(ra * 8 + (cg ^ (ra & 7))) * 8]);
#pragma unroll
            for (int nt = 0; nt < 4; nt++) {
                int rb = nt * 16 + rl;
                bf16x8 bfr = *(const bf16x8*)(&Bs[b][(rb * 8 + (cg ^ (rb & 7))) * 8]);
                acc[nt] = __builtin_amdgcn_mfma_f32_16x16x32_bf16(af, bfr, acc[nt], 0, 0, 0);
            }
        }
    }
    // epilogue: bias, transposed bf16 store, s1/s2 row-dot partials
    const int head = bn >> 7;
    const int row_base = bm + w * 16 + o * 4;
    float p1[4] = {0.f, 0.f, 0.f, 0.f}, p2[4] = {0.f, 0.f, 0.f, 0.f};
#pragma unroll
    for (int nt = 0; nt < 4; nt++) {
        int col = bn + nt * 16 + rl;
        float bv = bias[col];
        float a1v = a1[col] * LOG2E, a2v = a2[col] * LOG2E;
        bf16x4 hv;
#pragma unroll
        for (int r4 = 0; r4 < 4; r4++) {
            float h = acc[nt][r4] + bv;
            hv[r4] = (__bf16)h;
            p1[r4] += h * a1v;
            p2[r4] += h * a2v;
        }
        *(bf16x4*)(Ht + (size_t)col * M + row_base) = hv;
    }
#pragma unroll
    for (int r4 = 0; r4 < 4; r4++)
#pragma unroll
        for (int off = 1; off < 16; off <<= 1) {
            p1[r4] += __shfl_xor(p1[r4], off, 64);
            p2[r4] += __shfl_xor(p2[r4], off, 64);
        }
    if (rl == 0)
#pragma unroll
        for (int r4 = 0; r4 < 4; r4++) {
            atomicAdd(&s1[(size_t)head * M + row_base + r4], p1[r4]);
            atomicAdd(&s2[(size_t)head * M + row_base + r4], p2[r4]);
        }
}

// ---------------- global max of s2 per head ----------------
__global__ void smax_kernel(const float* __restrict__ s2, float* __restrict__ s2max) {
    const float* p = s2 + (size_t)blockIdx.x * NN;
    int t = threadIdx.x;
    float m = -INFINITY;
    for (int i = t; i < NN; i += 256) m = fmaxf(m, p[i]);
#pragma unroll
    for (int off = 1; off < 64; off <<= 1) m = fmaxf(m, __shfl_xor(m, off, 64));
    __shared__ float red[4];
    if ((t & 63) == 0) red[t >> 6] = m;
    __syncthreads();
    if (t == 0) s2max[blockIdx.x] = fmaxf(fmaxf(red[0], red[1]), fmaxf(red[2], red[3]));
}

// ---------------- MFMA attention, fragment-reuse, j-split partials ----------------
// 64-row blocks, 4 waves. Wave w produces P A-frags for rows [w*16, w*16+16)
// and consumes n-tiles [w*NTW*16, (w+1)*NTW*16) for ALL 4 m-tiles.
// Round-4: T14 prefetch WITHOUT the round-2/3 scratch spills. R3 proved the
// 80 µs regression was NOT the stagger (lockstep restored, still 80 µs,
// WRITE 67 MB vs 16.6 expected with identical store code): the struct PLoad
// live across the MFMA cluster spilled to scratch (private-segment traffic
// explains the +50 MB writes / +12 MB fetches and the VALUBusy collapse).
// Fixes:
//  * FLAT prefetch state: named regs (aw, sA0/sB0/sA1/sB1, fc0/fc1/fn0/fn1),
//    no struct-by-value, no runtime-indexed arrays -> guaranteed VGPRs.
//  * kt-OUTER MFMA loop: bfr live range 16 -> 8 VGPRs (same ds_read count),
//    keeping total demand under the 128-VGPR cap of 4 waves/EU.
// Kept: lockstep tile order, exp2 prescale, u0/v0 fold, deferred lacc reduce,
// setprio around MFMA, lgkm-only B2.
template<int FH, int JSPLIT>
__global__ __launch_bounds__(256, 4) void attn_kernel(
    const __bf16* __restrict__ Htg,               // [heads*FH][NN]
    const unsigned long long* __restrict__ adj_bits,
    const float* __restrict__ s1_all, const float* __restrict__ s2_all,
    const float* __restrict__ s2max_all, const float* __restrict__ ab_all,
    __bf16* __restrict__ accp,                    // [JSPLIT][NN][ldo]
    float* __restrict__ lg,                       // [heads*JSPLIT][NN]
    int ldo)
{
    constexpr int NJT = NN / 64 / JSPLIT;         // 16 (layer1) / 4 (layer2)
    constexpr int NTW = FH / 64;                  // n-tiles per wave (128->2, 64->1)
    const int head = blockIdx.y;
    const int js   = blockIdx.z;
    const int row0 = blockIdx.x * 64;
    const int jt0  = js * NJT;
    const int tid = threadIdx.x;
    const int w = tid >> 6, l = tid & 63, o = l >> 4, rl = l & 15;
    const int myrow = row0 + w * 16 + rl;         // producer row (mt = w)

    __shared__ __attribute__((aligned(16))) __bf16 hbuf[2][FH * 64];
    __shared__ __attribute__((aligned(16))) __bf16 plds[8 * 64 * 8];   // [mt*2+kt][lane]*8

    const float* s2 = s2_all + (size_t)head * NN;
    const __bf16* hg = Htg + (size_t)head * FH * NN;
    // s1/s2 already carry the LOG2E scale from the GEMM epilogue; ab scaled here.
    const float s1r = s1_all[(size_t)head * NN + myrow] + ab_all[head] * LOG2E;
    float mrow; { float x = s1r + s2max_all[head]; mrow = fmaxf(x, 0.2f * x); }
    const float u0 = s1r - mrow;                  // e-mrow = max(s+u0, fma(.2,s,v0))
    const float v0 = fmaf(0.2f, s1r, -mrow);
    float lacc = 0.f;                             // per-lane partial; reduced at end
    f32x4 acc[4][NTW] = {};

    // ---- flat prefetch state (no struct, no runtime indices -> stays in VGPRs)
    unsigned long long aw;                        // adj word for next-mathed tile
    f32x4 sA0, sB0, sA1, sB1;                     // s2[jt*64 + kt*32 + o*8 ..+8)
    bf16x8 fc0, fc1;                              // current tile's P frags (kt=0,1)
    bf16x8 fn0, fn1;                              // next tile's P frags

    auto PLOAD = [&](int jt) {
        aw = adj_bits[(size_t)myrow * 64 + jt];
        const float* sp = s2 + jt * 64 + o * 8;
        sA0 = *(const f32x4*)(sp);       sB0 = *(const f32x4*)(sp + 4);
        sA1 = *(const f32x4*)(sp + 32);  sB1 = *(const f32x4*)(sp + 36);
    };
    auto PMATH = [&](bf16x8& f0, bf16x8& f1) {
        float ps = 0.f;
        {
            unsigned int mb = (unsigned int)(aw >> (o * 8)) & 0xFFu;      // kt=0
#pragma unroll
            for (int q = 0; q < 8; q++) {
                float s = (q < 4) ? sA0[q] : sB0[q - 4];
                float t = fmaxf(s + u0, fmaf(0.2f, s, v0));
                t = ((mb >> q) & 1u) ? t : -1.0e20f;
                float p = EXP2(t);
                f0[q] = (__bf16)p; ps += p;
            }
        }
        {
            unsigned int mb = (unsigned int)(aw >> (32 + o * 8)) & 0xFFu; // kt=1
#pragma unroll
            for (int q = 0; q < 8; q++) {
                float s = (q < 4) ? sA1[q] : sB1[q - 4];
                float t = fmaxf(s + u0, fmaf(0.2f, s, v0));
                t = ((mb >> q) & 1u) ? t : -1.0e20f;
                float p = EXP2(t);
                f1[q] = (__bf16)p; ps += p;
            }
        }
        lacc += ps;
    };

    stage_tile<FH>(hg + (size_t)jt0 * 64, &hbuf[0][0], tid);
    PLOAD(jt0);
    PMATH(fc0, fc1);                              // prologue: tile 0
    PLOAD(jt0 + 1);                               // NJT >= 2 always (16 / 4)

    for (int jl = 0; jl < NJT; jl++) {
        const int b = jl & 1;
        const int jt = jt0 + jl;
        // publish this tile's P fragments (plds free: previous B2 passed)
        *(bf16x8*)(&plds[((w * 2 + 0) * 64 + l) * 8]) = fc0;
        *(bf16x8*)(&plds[((w * 2 + 1) * 64 + l) * 8]) = fc1;
        __syncthreads();   // B1: plds visible; hbuf[b] DMA + reg prefetch drained
        if (jl + 1 < NJT) {
            stage_tile<FH>(hg + (size_t)(jt + 1) * 64, &hbuf[b ^ 1][0], tid);
            PMATH(fn0, fn1);                      // math on regs loaded last iter
        }
        if (jl + 2 < NJT) PLOAD(jt + 2);          // prefetch (drains at next B1)
        __builtin_amdgcn_s_setprio(1);
#pragma unroll
        for (int kt = 0; kt < 2; kt++) {          // kt-outer: bfr live = 8 VGPRs
            bf16x8 b0, b1;
            {
                int f = (w * NTW + 0) * 16 + rl;
                int slot = (kt * 4 + o) ^ (rl & 7);
                b0 = *(const bf16x8*)(&hbuf[b][(f * 8 + slot) * 8]);
            }
            if constexpr (NTW > 1) {
                int f = (w * NTW + 1) * 16 + rl;
                int slot = (kt * 4 + o) ^ (rl & 7);
                b1 = *(const bf16x8*)(&hbuf[b][(f * 8 + slot) * 8]);
            }
#pragma unroll
            for (int mt = 0; mt < 4; mt++) {
                bf16x8 af = (mt == w) ? (kt ? fc1 : fc0)
                          : *(const bf16x8*)(&plds[((mt * 2 + kt) * 64 + l) * 8]);
                acc[mt][0] = __builtin_amdgcn_mfma_f32_16x16x32_bf16(
                    af, b0, acc[mt][0], 0, 0, 0);
                if constexpr (NTW > 1)
                    acc[mt][1] = __builtin_amdgcn_mfma_f32_16x16x32_bf16(
                        af, b1, acc[mt][1], 0, 0, 0);
            }
        }
        __builtin_amdgcn_s_setprio(0);
        barrier_lgkm();    // B2: plds reads done; DMA prefetch stays in flight
        fc0 = fn0; fc1 = fn1;
    }
    // ---- epilogue: cross-lane lacc reduce (deferred from loop) ----
    lacc += __shfl_xor(lacc, 16, 64);
    lacc += __shfl_xor(lacc, 32, 64);
    if (l < 16) lg[((size_t)head * JSPLIT + js) * NN + row0 + w * 16 + l] = lacc;
#pragma unroll
    for (int mt = 0; mt < 4; mt++)
#pragma unroll
        for (int ntl = 0; ntl < NTW; ntl++)
#pragma unroll
            for (int r4 = 0; r4 < 4; r4++) {
                int grow = row0 + mt * 16 + o * 4 + r4;
                int gcol = head * FH + (w * NTW + ntl) * 16 + rl;
                accp[((size_t)js * NN + grow) * ldo + gcol] = (__bf16)acc[mt][ntl][r4];
            }
}

// ---------------- combine layer-1 partials: normalize + elu -> bf16 [N][512] ----------------
__global__ void combine1_kernel(const __bf16* __restrict__ accp, const float* __restrict__ lg,
                                __bf16* __restrict__ outb) {
    int gid = blockIdx.x * 256 + threadIdx.x;        // N * 128
    int row = gid >> 7, c4 = (gid & 127) * 4;
    int head = c4 >> 7;
    float lsum = 0.f;
#pragma unroll
    for (int js = 0; js < 4; js++) lsum += lg[((size_t)head * 4 + js) * NN + row];
    float inv = lsum > 0.f ? 1.f / lsum : 0.f;
    float v[4] = {0.f, 0.f, 0.f, 0.f};
#pragma unroll
    for (int js = 0; js < 4; js++) {
        bf16x4 t = *(const bf16x4*)(accp + ((size_t)js * NN + row) * 512 + c4);
#pragma unroll
        for (int q = 0; q < 4; q++) v[q] += (float)t[q];
    }
    bf16x4 ob;
#pragma unroll
    for (int q = 0; q < 4; q++) {
        float x = v[q] * inv;
        x = x > 0.f ? x : __expf(x) - 1.f;
        ob[q] = (__bf16)x;
    }
    *(bf16x4*)(outb + (size_t)row * 512 + c4) = ob;
}

// ---------------- combine layer-2 partials + elu + log_softmax -> out ----------------
__global__ void combine2_kernel(const __bf16* __restrict__ accp, const float* __restrict__ lg,
                                float* __restrict__ out) {
    int row = (blockIdx.x * 256 + threadIdx.x) >> 6;
    int lane = threadIdx.x & 63;
    if (row >= NN) return;
    float lsum = 0.f, v = 0.f;
#pragma unroll
    for (int js = 0; js < 16; js++) {
        lsum += lg[(size_t)js * NN + row];
        v += (float)accp[((size_t)js * NN + row) * 64 + lane];
    }
    float inv = lsum > 0.f ? 1.f / lsum : 0.f;
    v *= inv;
    v = v > 0.f ? v : __expf(v) - 1.f;
    float m = v;
#pragma unroll
    for (int off = 1; off < 64; off <<= 1) m = fmaxf(m, __shfl_xor(m, off, 64));
    float ex = __expf(v - m);
    float s = ex;
#pragma unroll
    for (int off = 1; off < 64; off <<= 1) s += __shfl_xor(s, off, 64);
    out[(size_t)row * 64 + lane] = v - m - __logf(s);
}

extern "C" void kernel_launch(void* const* d_in, const int* in_sizes, int n_in,
                              void* d_out, int out_size, void* d_ws, size_t ws_size,
                              hipStream_t stream) {
    const float* X    = (const float*)d_in[0];
    const int*   adj  = (const int*)d_in[1];
    const float* W_h  = (const float*)d_in[2];
    const float* b_h  = (const float*)d_in[3];
    const float* a1_h = (const float*)d_in[4];
    const float* a2_h = (const float*)d_in[5];
    const float* ab_h = (const float*)d_in[6];
    const float* W_o  = (const float*)d_in[7];
    const float* b_o  = (const float*)d_in[8];
    const float* a1_o = (const float*)d_in[9];
    const float* a2_o = (const float*)d_in[10];
    const float* ab_o = (const float*)d_in[11];
    float* out = (float*)d_out;

    char* ws = (char*)d_ws;
    auto alloc = [&](size_t bytes) {
        char* p = ws; ws += (bytes + 255) & ~(size_t)255; return p;
    };
    unsigned long long* adj_bits = (unsigned long long*)alloc((size_t)NN * 64 * 8); // 2 MB
    __bf16* Bt1    = (__bf16*)alloc((size_t)512 * 512 * 2);     // 512 KB
    float*  biasp  = (float*)alloc(512 * 4);
    __bf16* Bt2    = (__bf16*)alloc((size_t)64 * 512 * 2);      // 64 KB
    __bf16* Xb     = (__bf16*)alloc((size_t)NN * 512 * 2);      // 4 MB
    float*  s1h    = (float*)alloc((size_t)4 * NN * 4);         // |-- contiguous,
    float*  s2h    = (float*)alloc((size_t)4 * NN * 4);         // |   one memset
    float*  s1o    = (float*)alloc((size_t)NN * 4);             // |   (160 KB)
    float*  s2o    = (float*)alloc((size_t)NN * 4);             // |
    float*  s2maxh = (float*)alloc(4 * 4);
    float*  s2maxo = (float*)alloc(4);
    __bf16* Htg    = (__bf16*)alloc((size_t)512 * NN * 2);      // 4 MB
    __bf16* accp1  = (__bf16*)alloc((size_t)4 * NN * 512 * 2);  // 16 MB
    float*  lg1    = (float*)alloc((size_t)16 * NN * 4);        // 256 KB
    __bf16* outhb  = (__bf16*)alloc((size_t)NN * 512 * 2);      // 4 MB
    __bf16* Ht2    = (__bf16*)alloc((size_t)64 * NN * 2);       // 512 KB
    __bf16* accp2  = (__bf16*)alloc((size_t)16 * NN * 64 * 2);  // 8 MB
    float*  lg2    = (float*)alloc((size_t)16 * NN * 4);        // 256 KB  (~40 MB)

    // 0. zero the atomic s1/s2 accumulators (contiguous block)
    hipMemsetAsync(s1h, 0, (size_t)(4 + 4 + 1 + 1) * NN * 4, stream);
    // 1. adjacency -> bitmasks (single read of the 67 MB int32 matrix)
    pack_adj_kernel<<<(NN * 64) / 4, 256, 0, stream>>>(adj, adj_bits);
    // 2. prepack weights (bf16, [n][k])
    prepack_kernel<<<1024, 256, 0, stream>>>(W_h, b_h, W_o, Bt1, biasp, Bt2);
    // 3. X -> bf16
    cast_bf16_kernel<<<(NN * 512 / 4) / 256, 256, 0, stream>>>(X, Xb);
    // 4. layer-1 GEMM fused: Htg (transposed bf16) + s1h/s2h atomics (LOG2E-scaled)
    gemm_fused_kernel<<<dim3(8, 64), 256, 0, stream>>>(
        Xb, Bt1, biasp, a1_h, a2_h, Htg, s1h, s2h, NN, 512, 512);
    // 5. per-head global s2 max
    smax_kernel<<<4, 256, 0, stream>>>(s2h, s2maxh);
    // 6. attention layer 1 partials (4 heads x 4 j-splits)
    attn_kernel<128, 4><<<dim3(NN / 64, 4, 4), 256, 0, stream>>>(
        Htg, adj_bits, s1h, s2h, s2maxh, ab_h, accp1, lg1, 512);
    // 7. combine -> elu -> bf16 concat features [N][512]
    combine1_kernel<<<(NN * 128) / 256, 256, 0, stream>>>(accp1, lg1, outhb);
    // 8. layer-2 GEMM fused: Ht2 (transposed bf16) + s1o/s2o atomics (LOG2E-scaled)
    gemm_fused_kernel<<<dim3(1, 64), 256, 0, stream>>>(
        outhb, Bt2, b_o, a1_o, a2_o, Ht2, s1o, s2o, NN, 64, 512);
    // 9. s2 max (output layer)
    smax_kernel<<<1, 256, 0, stream>>>(s2o, s2maxo);
    // 10. attention layer 2 partials (16 j-splits)
    attn_kernel<64, 16><<<dim3(NN / 64, 1, 16), 256, 0, stream>>>(
        Ht2, adj_bits, s1o, s2o, s2maxo, ab_o, accp2, lg2, 64);
    // 11. combine + elu + log_softmax -> out
    combine2_kernel<<<(NN * 64) / 256, 256, 0, stream>>>(accp2, lg2, out);
}

// Round 5
// 218.972 us; speedup vs baseline: 1.2344x; 1.0365x over previous
//
#include <hip/hip_runtime.h>
#include <math.h>

#define NN 4096   // nodes
#define LOG2E 1.44269504088896340736f

using f32x2  = __attribute__((ext_vector_type(2))) float;
using f32x4  = __attribute__((ext_vector_type(4))) float;
using bf16x4 = __attribute__((ext_vector_type(4))) __bf16;
using bf16x8 = __attribute__((ext_vector_type(8))) __bf16;

// exp2 in one v_exp_f32 (inputs are pre-scaled by log2e)
#if __has_builtin(__builtin_amdgcn_exp2f)
#define EXP2(x) __builtin_amdgcn_exp2f(x)
#else
#define EXP2(x) __expf((x) * 0.6931471805599453f)
#endif

// ---------------- async global->LDS staging (16B, XOR-swizzled chunks) ----------------
// Row f of 64 bf16 = 8 chunks of 8; LDS slot s of row f holds global chunk s^(f&7).
template<int FH>
__device__ __forceinline__ void stage_tile(const __bf16* __restrict__ hgp,
                                           __bf16* dst, int tid) {
#pragma unroll
    for (int it = 0; it < FH / 32; it++) {
        int c = tid + it * 256;
        int f = c >> 3, sl = c & 7;
        int g = sl ^ (f & 7);
        __builtin_amdgcn_global_load_lds(
            (const __attribute__((address_space(1))) void*)(hgp + (size_t)f * NN + g * 8),
            (__attribute__((address_space(3))) void*)(dst + (size_t)c * 8), 16, 0, 0);
    }
}

__device__ __forceinline__ void stage_g(const __bf16* __restrict__ base, int ldk,
                                        __bf16* dst, int tid) {
#pragma unroll
    for (int it = 0; it < 2; it++) {
        int c = tid + it * 256;
        int f = c >> 3, sl = c & 7;
        int g = sl ^ (f & 7);
        __builtin_amdgcn_global_load_lds(
            (const __attribute__((address_space(1))) void*)(base + (size_t)f * ldk + g * 8),
            (__attribute__((address_space(3))) void*)(dst + (size_t)c * 8), 16, 0, 0);
    }
}

// ---------------- adjacency -> bitmask ----------------
__global__ void pack_adj_kernel(const int* __restrict__ adj,
                                unsigned long long* __restrict__ bits) {
    int gw = (blockIdx.x * blockDim.x + threadIdx.x) >> 6;
    int lane = threadIdx.x & 63;
    int v = adj[(size_t)gw * 64 + lane];
    unsigned long long m = __ballot(v > 0);
    if (lane == 0) bits[gw] = m;
}

// ---------------- prepack: W_h -> Bt1[n=512][k=512] bf16, W_o -> Bt2[n=64][k=512] ----
__global__ void prepack_kernel(const float* __restrict__ W_h, const float* __restrict__ b_h,
                               const float* __restrict__ W_o,
                               __bf16* __restrict__ Bt1, float* __restrict__ biasp,
                               __bf16* __restrict__ Bt2) {
    int idx = blockIdx.x * 256 + threadIdx.x;   // 512*512
    {
        int n = idx >> 9, k = idx & 511;
        int h = n >> 7, f = n & 127;
        Bt1[idx] = (__bf16)W_h[(size_t)h * 512 * 128 + k * 128 + f];
    }
    if (idx < 64 * 512) {
        int n = idx >> 9, k = idx & 511;
        Bt2[idx] = (__bf16)W_o[k * 64 + n];
    }
    if (idx < 512) biasp[idx] = b_h[idx];
}

// ---------------- fp32 -> bf16 cast ----------------
__global__ void cast_bf16_kernel(const float* __restrict__ src, __bf16* __restrict__ dst) {
    int i = blockIdx.x * 256 + threadIdx.x;
    f32x4 v = *(const f32x4*)(src + (size_t)i * 4);
    bf16x4 o;
#pragma unroll
    for (int q = 0; q < 4; q++) o[q] = (__bf16)v[q];
    *(bf16x4*)(dst + (size_t)i * 4) = o;
}

// ---------------- fused bf16 MFMA GEMM ----------------
// Ht[col][row] = bf16( (A @ Bt^T)[row][col] + bias[col] )   (transposed store)
// s1[head][row] += sum_col h*a1[col]*LOG2E, s2 likewise (pre-scaled for exp2;
// lrelu is positively homogeneous so the scale commutes through it exactly).
__global__ __launch_bounds__(256) void gemm_fused_kernel(
    const __bf16* __restrict__ A, const __bf16* __restrict__ Bt,
    const float* __restrict__ bias,
    const float* __restrict__ a1, const float* __restrict__ a2,
    __bf16* __restrict__ Ht, float* __restrict__ s1, float* __restrict__ s2,
    int M, int N, int K)
{
    __shared__ __attribute__((aligned(16))) __bf16 As[2][64 * 64];
    __shared__ __attribute__((aligned(16))) __bf16 Bs[2][64 * 64];
    const int tid = threadIdx.x, w = tid >> 6, l = tid & 63, o = l >> 4, rl = l & 15;
    const int bm = blockIdx.y * 64, bn = blockIdx.x * 64;
    f32x4 acc[4] = {};
    stage_g(A + (size_t)bm * K, K, &As[0][0], tid);
    stage_g(Bt + (size_t)bn * K, K, &Bs[0][0], tid);
    const int KB = K / 64;
    for (int kb = 0; kb < KB; kb++) {
        int b = kb & 1;
        __syncthreads();
        if (kb + 1 < KB) {
            stage_g(A + (size_t)bm * K + (kb + 1) * 64, K, &As[b ^ 1][0], tid);
            stage_g(Bt + (size_t)bn * K + (kb + 1) * 64, K, &Bs[b ^ 1][0], tid);
        }
#pragma unroll
        for (int kt = 0; kt < 2; kt++) {
            int ra = w * 16 + rl;
            int cg = kt * 4 + o;
            bf16x8 af = *(const bf16x8*)(&As[b][(ra * 8 + (cg ^ (ra & 7))) * 8]);
#pragma unroll
            for (int nt = 0; nt < 4; nt++) {
                int rb = nt * 16 + rl;
                bf16x8 bfr = *(const bf16x8*)(&Bs[b][(rb * 8 + (cg ^ (rb & 7))) * 8]);
                acc[nt] = __builtin_amdgcn_mfma_f32_16x16x32_bf16(af, bfr, acc[nt], 0, 0, 0);
            }
        }
    }
    // epilogue: bias, transposed bf16 store, s1/s2 row-dot partials
    const int head = bn >> 7;
    const int row_base = bm + w * 16 + o * 4;
    float p1[4] = {0.f, 0.f, 0.f, 0.f}, p2[4] = {0.f, 0.f, 0.f, 0.f};
#pragma unroll
    for (int nt = 0; nt < 4; nt++) {
        int col = bn + nt * 16 + rl;
        float bv = bias[col];
        float a1v = a1[col] * LOG2E, a2v = a2[col] * LOG2E;
        bf16x4 hv;
#pragma unroll
        for (int r4 = 0; r4 < 4; r4++) {
            float h = acc[nt][r4] + bv;
            hv[r4] = (__bf16)h;
            p1[r4] += h * a1v;
            p2[r4] += h * a2v;
        }
        *(bf16x4*)(Ht + (size_t)col * M + row_base) = hv;
    }
#pragma unroll
    for (int r4 = 0; r4 < 4; r4++)
#pragma unroll
        for (int off = 1; off < 16; off <<= 1) {
            p1[r4] += __shfl_xor(p1[r4], off, 64);
            p2[r4] += __shfl_xor(p2[r4], off, 64);
        }
    if (rl == 0)
#pragma unroll
        for (int r4 = 0; r4 < 4; r4++) {
            atomicAdd(&s1[(size_t)head * M + row_base + r4], p1[r4]);
            atomicAdd(&s2[(size_t)head * M + row_base + r4], p2[r4]);
        }
}

// ---------------- global max of s2 per head ----------------
__global__ void smax_kernel(const float* __restrict__ s2, float* __restrict__ s2max) {
    const float* p = s2 + (size_t)blockIdx.x * NN;
    int t = threadIdx.x;
    float m = -INFINITY;
    for (int i = t; i < NN; i += 256) m = fmaxf(m, p[i]);
#pragma unroll
    for (int off = 1; off < 64; off <<= 1) m = fmaxf(m, __shfl_xor(m, off, 64));
    __shared__ float red[4];
    if ((t & 63) == 0) red[t >> 6] = m;
    __syncthreads();
    if (t == 0) s2max[blockIdx.x] = fmaxf(fmaxf(red[0], red[1]), fmaxf(red[2], red[3]));
}

// ---------------- MFMA attention, SELF-CONSUME, j-split partials ----------------
// Round-5 restructure. Evidence: R1 (VALU cut, dur flat) and R4 (load prefetch,
// dur flat) refute VALU-throughput and load-latency theories. Arithmetic: per
// SIMD 120k cycles, VALU-busy 57k, MFMA 16k, ~45k idle -> the 2-barrier/iter
// producer/consumer lockstep (wave w's MFMA needs ALL waves' plds) forces all
// 16 waves/CU into the same phase: VALU rush then matrix rush, no overlap.
// Fix: wave w keeps its own P fragments (it already computes exactly the
// A-frag of m-tile w) and computes m-tile w across ALL n-tiles (NTL = FH/16).
// Same 16 MFMAs/wave/iter, identical output coverage, but:
//  * NO plds, NO cross-wave P dependency -> produce->consume is wave-local.
//  * ONE barrier per iter (hbuf double-buffer only) -> waves slip freely
//    within the window; one wave's PMATH overlaps another's MFMA.
//  * LDS 40 KB -> 32 KB (layer1), 16 KB (layer2): more blocks/CU possible.
// Kept: lockstep tile order, exp2 prescale, u0/v0 fold, deferred lacc reduce,
// flat-reg s2/adj prefetch (1 tile ahead), setprio around MFMA.
template<int FH, int JSPLIT>
__global__ __launch_bounds__(256, 4) void attn_kernel(
    const __bf16* __restrict__ Htg,               // [heads*FH][NN]
    const unsigned long long* __restrict__ adj_bits,
    const float* __restrict__ s1_all, const float* __restrict__ s2_all,
    const float* __restrict__ s2max_all, const float* __restrict__ ab_all,
    __bf16* __restrict__ accp,                    // [JSPLIT][NN][ldo]
    float* __restrict__ lg,                       // [heads*JSPLIT][NN]
    int ldo)
{
    constexpr int NJT = NN / 64 / JSPLIT;         // 16 (layer1) / 4 (layer2)
    constexpr int NTL = FH / 16;                  // n-tiles per wave (8 or 4)
    const int head = blockIdx.y;
    const int js   = blockIdx.z;
    const int row0 = blockIdx.x * 64;
    const int jt0  = js * NJT;
    const int tid = threadIdx.x;
    const int w = tid >> 6, l = tid & 63, o = l >> 4, rl = l & 15;
    const int myrow = row0 + w * 16 + rl;         // this wave's m-tile rows

    __shared__ __attribute__((aligned(16))) __bf16 hbuf[2][FH * 64];

    const float* s2 = s2_all + (size_t)head * NN;
    const __bf16* hg = Htg + (size_t)head * FH * NN;
    // s1/s2 already carry the LOG2E scale from the GEMM epilogue; ab scaled here.
    const float s1r = s1_all[(size_t)head * NN + myrow] + ab_all[head] * LOG2E;
    float mrow; { float x = s1r + s2max_all[head]; mrow = fmaxf(x, 0.2f * x); }
    const float u0 = s1r - mrow;                  // e-mrow = max(s+u0, fma(.2,s,v0))
    const float v0 = fmaf(0.2f, s1r, -mrow);
    float lacc = 0.f;                             // per-lane partial; reduced at end
    f32x4 acc[NTL] = {};                          // m-tile w, all n-tiles

    // ---- flat prefetch state (named regs only -> guaranteed VGPRs)
    unsigned long long aw;
    f32x4 sA0, sB0, sA1, sB1;                     // s2[jt*64 + kt*32 + o*8 ..+8)

    auto PLOAD = [&](int jt) {
        aw = adj_bits[(size_t)myrow * 64 + jt];
        const float* sp = s2 + jt * 64 + o * 8;
        sA0 = *(const f32x4*)(sp);       sB0 = *(const f32x4*)(sp + 4);
        sA1 = *(const f32x4*)(sp + 32);  sB1 = *(const f32x4*)(sp + 36);
    };
    auto PMATH = [&](bf16x8& f0, bf16x8& f1) {
        float ps = 0.f;
        {
            unsigned int mb = (unsigned int)(aw >> (o * 8)) & 0xFFu;      // kt=0
#pragma unroll
            for (int q = 0; q < 8; q++) {
                float s = (q < 4) ? sA0[q] : sB0[q - 4];
                float t = fmaxf(s + u0, fmaf(0.2f, s, v0));
                t = ((mb >> q) & 1u) ? t : -1.0e20f;
                float p = EXP2(t);
                f0[q] = (__bf16)p; ps += p;
            }
        }
        {
            unsigned int mb = (unsigned int)(aw >> (32 + o * 8)) & 0xFFu; // kt=1
#pragma unroll
            for (int q = 0; q < 8; q++) {
                float s = (q < 4) ? sA1[q] : sB1[q - 4];
                float t = fmaxf(s + u0, fmaf(0.2f, s, v0));
                t = ((mb >> q) & 1u) ? t : -1.0e20f;
                float p = EXP2(t);
                f1[q] = (__bf16)p; ps += p;
            }
        }
        lacc += ps;
    };

    stage_tile<FH>(hg + (size_t)jt0 * 64, &hbuf[0][0], tid);
    PLOAD(jt0);

    for (int jl = 0; jl < NJT; jl++) {
        const int b = jl & 1;
        const int jt = jt0 + jl;
        // ONE barrier: hbuf[b] DMA drained (vmcnt 0); hbuf[b^1] free to overwrite
        __syncthreads();
        if (jl + 1 < NJT)
            stage_tile<FH>(hg + (size_t)(jt + 1) * 64, &hbuf[b ^ 1][0], tid);
        // produce this tile's P fragments from regs prefetched last iteration
        bf16x8 fc0, fc1;
        PMATH(fc0, fc1);
        if (jl + 1 < NJT) PLOAD(jt + 1);          // covered by MFMA cluster below
        // consume: own m-tile, ALL n-tiles (wave-local, no cross-wave sync)
        __builtin_amdgcn_s_setprio(1);
#pragma unroll
        for (int ntl = 0; ntl < NTL; ntl++) {
            int f = ntl * 16 + rl;
            int s0 = o ^ (rl & 7);                // kt=0 slot
            int s1 = (4 + o) ^ (rl & 7);          // kt=1 slot
            bf16x8 b0 = *(const bf16x8*)(&hbuf[b][(f * 8 + s0) * 8]);
            bf16x8 b1 = *(const bf16x8*)(&hbuf[b][(f * 8 + s1) * 8]);
            acc[ntl] = __builtin_amdgcn_mfma_f32_16x16x32_bf16(fc0, b0, acc[ntl], 0, 0, 0);
            acc[ntl] = __builtin_amdgcn_mfma_f32_16x16x32_bf16(fc1, b1, acc[ntl], 0, 0, 0);
        }
        __builtin_amdgcn_s_setprio(0);
    }
    // ---- epilogue: cross-lane lacc reduce (deferred from loop) ----
    lacc += __shfl_xor(lacc, 16, 64);
    lacc += __shfl_xor(lacc, 32, 64);
    if (l < 16) lg[((size_t)head * JSPLIT + js) * NN + row0 + w * 16 + l] = lacc;
#pragma unroll
    for (int ntl = 0; ntl < NTL; ntl++)
#pragma unroll
        for (int r4 = 0; r4 < 4; r4++) {
            int grow = row0 + w * 16 + o * 4 + r4;
            int gcol = head * FH + ntl * 16 + rl;
            accp[((size_t)js * NN + grow) * ldo + gcol] = (__bf16)acc[ntl][r4];
        }
}

// ---------------- combine layer-1 partials: normalize + elu -> bf16 [N][512] ----------------
__global__ void combine1_kernel(const __bf16* __restrict__ accp, const float* __restrict__ lg,
                                __bf16* __restrict__ outb) {
    int gid = blockIdx.x * 256 + threadIdx.x;        // N * 128
    int row = gid >> 7, c4 = (gid & 127) * 4;
    int head = c4 >> 7;
    float lsum = 0.f;
#pragma unroll
    for (int js = 0; js < 4; js++) lsum += lg[((size_t)head * 4 + js) * NN + row];
    float inv = lsum > 0.f ? 1.f / lsum : 0.f;
    float v[4] = {0.f, 0.f, 0.f, 0.f};
#pragma unroll
    for (int js = 0; js < 4; js++) {
        bf16x4 t = *(const bf16x4*)(accp + ((size_t)js * NN + row) * 512 + c4);
#pragma unroll
        for (int q = 0; q < 4; q++) v[q] += (float)t[q];
    }
    bf16x4 ob;
#pragma unroll
    for (int q = 0; q < 4; q++) {
        float x = v[q] * inv;
        x = x > 0.f ? x : __expf(x) - 1.f;
        ob[q] = (__bf16)x;
    }
    *(bf16x4*)(outb + (size_t)row * 512 + c4) = ob;
}

// ---------------- combine layer-2 partials + elu + log_softmax -> out ----------------
__global__ void combine2_kernel(const __bf16* __restrict__ accp, const float* __restrict__ lg,
                                float* __restrict__ out) {
    int row = (blockIdx.x * 256 + threadIdx.x) >> 6;
    int lane = threadIdx.x & 63;
    if (row >= NN) return;
    float lsum = 0.f, v = 0.f;
#pragma unroll
    for (int js = 0; js < 16; js++) {
        lsum += lg[(size_t)js * NN + row];
        v += (float)accp[((size_t)js * NN + row) * 64 + lane];
    }
    float inv = lsum > 0.f ? 1.f / lsum : 0.f;
    v *= inv;
    v = v > 0.f ? v : __expf(v) - 1.f;
    float m = v;
#pragma unroll
    for (int off = 1; off < 64; off <<= 1) m = fmaxf(m, __shfl_xor(m, off, 64));
    float ex = __expf(v - m);
    float s = ex;
#pragma unroll
    for (int off = 1; off < 64; off <<= 1) s += __shfl_xor(s, off, 64);
    out[(size_t)row * 64 + lane] = v - m - __logf(s);
}

extern "C" void kernel_launch(void* const* d_in, const int* in_sizes, int n_in,
                              void* d_out, int out_size, void* d_ws, size_t ws_size,
                              hipStream_t stream) {
    const float* X    = (const float*)d_in[0];
    const int*   adj  = (const int*)d_in[1];
    const float* W_h  = (const float*)d_in[2];
    const float* b_h  = (const float*)d_in[3];
    const float* a1_h = (const float*)d_in[4];
    const float* a2_h = (const float*)d_in[5];
    const float* ab_h = (const float*)d_in[6];
    const float* W_o  = (const float*)d_in[7];
    const float* b_o  = (const float*)d_in[8];
    const float* a1_o = (const float*)d_in[9];
    const float* a2_o = (const float*)d_in[10];
    const float* ab_o = (const float*)d_in[11];
    float* out = (float*)d_out;

    char* ws = (char*)d_ws;
    auto alloc = [&](size_t bytes) {
        char* p = ws; ws += (bytes + 255) & ~(size_t)255; return p;
    };
    unsigned long long* adj_bits = (unsigned long long*)alloc((size_t)NN * 64 * 8); // 2 MB
    __bf16* Bt1    = (__bf16*)alloc((size_t)512 * 512 * 2);     // 512 KB
    float*  biasp  = (float*)alloc(512 * 4);
    __bf16* Bt2    = (__bf16*)alloc((size_t)64 * 512 * 2);      // 64 KB
    __bf16* Xb     = (__bf16*)alloc((size_t)NN * 512 * 2);      // 4 MB
    float*  s1h    = (float*)alloc((size_t)4 * NN * 4);         // |-- contiguous,
    float*  s2h    = (float*)alloc((size_t)4 * NN * 4);         // |   one memset
    float*  s1o    = (float*)alloc((size_t)NN * 4);             // |   (160 KB)
    float*  s2o    = (float*)alloc((size_t)NN * 4);             // |
    float*  s2maxh = (float*)alloc(4 * 4);
    float*  s2maxo = (float*)alloc(4);
    __bf16* Htg    = (__bf16*)alloc((size_t)512 * NN * 2);      // 4 MB
    __bf16* accp1  = (__bf16*)alloc((size_t)4 * NN * 512 * 2);  // 16 MB
    float*  lg1    = (float*)alloc((size_t)16 * NN * 4);        // 256 KB
    __bf16* outhb  = (__bf16*)alloc((size_t)NN * 512 * 2);      // 4 MB
    __bf16* Ht2    = (__bf16*)alloc((size_t)64 * NN * 2);       // 512 KB
    __bf16* accp2  = (__bf16*)alloc((size_t)16 * NN * 64 * 2);  // 8 MB
    float*  lg2    = (float*)alloc((size_t)16 * NN * 4);        // 256 KB  (~40 MB)

    // 0. zero the atomic s1/s2 accumulators (contiguous block)
    hipMemsetAsync(s1h, 0, (size_t)(4 + 4 + 1 + 1) * NN * 4, stream);
    // 1. adjacency -> bitmasks (single read of the 67 MB int32 matrix)
    pack_adj_kernel<<<(NN * 64) / 4, 256, 0, stream>>>(adj, adj_bits);
    // 2. prepack weights (bf16, [n][k])
    prepack_kernel<<<1024, 256, 0, stream>>>(W_h, b_h, W_o, Bt1, biasp, Bt2);
    // 3. X -> bf16
    cast_bf16_kernel<<<(NN * 512 / 4) / 256, 256, 0, stream>>>(X, Xb);
    // 4. layer-1 GEMM fused: Htg (transposed bf16) + s1h/s2h atomics (LOG2E-scaled)
    gemm_fused_kernel<<<dim3(8, 64), 256, 0, stream>>>(
        Xb, Bt1, biasp, a1_h, a2_h, Htg, s1h, s2h, NN, 512, 512);
    // 5. per-head global s2 max
    smax_kernel<<<4, 256, 0, stream>>>(s2h, s2maxh);
    // 6. attention layer 1 partials (4 heads x 4 j-splits)
    attn_kernel<128, 4><<<dim3(NN / 64, 4, 4), 256, 0, stream>>>(
        Htg, adj_bits, s1h, s2h, s2maxh, ab_h, accp1, lg1, 512);
    // 7. combine -> elu -> bf16 concat features [N][512]
    combine1_kernel<<<(NN * 128) / 256, 256, 0, stream>>>(accp1, lg1, outhb);
    // 8. layer-2 GEMM fused: Ht2 (transposed bf16) + s1o/s2o atomics (LOG2E-scaled)
    gemm_fused_kernel<<<dim3(1, 64), 256, 0, stream>>>(
        outhb, Bt2, b_o, a1_o, a2_o, Ht2, s1o, s2o, NN, 64, 512);
    // 9. s2 max (output layer)
    smax_kernel<<<1, 256, 0, stream>>>(s2o, s2maxo);
    // 10. attention layer 2 partials (16 j-splits)
    attn_kernel<64, 16><<<dim3(NN / 64, 1, 16), 256, 0, stream>>>(
        Ht2, adj_bits, s1o, s2o, s2maxo, ab_o, accp2, lg2, 64);
    // 11. combine + elu + log_softmax -> out
    combine2_kernel<<<(NN * 64) / 256, 256, 0, stream>>>(accp2, lg2, out);
}

// Round 6
// 209.251 us; speedup vs baseline: 1.2917x; 1.0465x over previous
//
#include <hip/hip_runtime.h>
#include <math.h>

#define NN 4096   // nodes
#define LOG2E 1.44269504088896340736f

using f32x4  = __attribute__((ext_vector_type(4))) float;
using bf16x4 = __attribute__((ext_vector_type(4))) __bf16;
using bf16x8 = __attribute__((ext_vector_type(8))) __bf16;

// exp2 in one v_exp_f32 (inputs are pre-scaled by log2e)
#if __has_builtin(__builtin_amdgcn_exp2f)
#define EXP2(x) __builtin_amdgcn_exp2f(x)
#else
#define EXP2(x) __expf((x) * 0.6931471805599453f)
#endif

// ---------------- async global->LDS staging (16B, XOR-swizzled chunks) ----------------
// Row f of 64 bf16 = 8 chunks of 8; LDS slot s of row f holds global chunk s^(f&7).
template<int FH>
__device__ __forceinline__ void stage_tile(const __bf16* __restrict__ hgp,
                                           __bf16* dst, int tid) {
#pragma unroll
    for (int it = 0; it < FH / 32; it++) {
        int c = tid + it * 256;
        int f = c >> 3, sl = c & 7;
        int g = sl ^ (f & 7);
        __builtin_amdgcn_global_load_lds(
            (const __attribute__((address_space(1))) void*)(hgp + (size_t)f * NN + g * 8),
            (__attribute__((address_space(3))) void*)(dst + (size_t)c * 8), 16, 0, 0);
    }
}

__device__ __forceinline__ void stage_g(const __bf16* __restrict__ base, int ldk,
                                        __bf16* dst, int tid) {
#pragma unroll
    for (int it = 0; it < 2; it++) {
        int c = tid + it * 256;
        int f = c >> 3, sl = c & 7;
        int g = sl ^ (f & 7);
        __builtin_amdgcn_global_load_lds(
            (const __attribute__((address_space(1))) void*)(base + (size_t)f * ldk + g * 8),
            (__attribute__((address_space(3))) void*)(dst + (size_t)c * 8), 16, 0, 0);
    }
}

// ---------------- fused prep: memset + prepack + cast + pack_adj in ONE dispatch ----
// Round-6: 12 -> 7 dispatches. All four tasks are mutually independent; the old
// pipeline paid 4 launch/tail latencies plus a 65536-workgroup pack_adj launch.
// Block-range partition:
//   [0, 1024):       W_h -> Bt1[n][k], W_o -> Bt2[n][k], biasp, zero s1/s2 accums
//   [1024, 3072):    X -> bf16 cast (f32x4 per thread)
//   [3072, 7168):    adjacency -> bitmasks, grid-strided (4 waves/block x 16 groups)
__global__ void prep_kernel(const int* __restrict__ adj, unsigned long long* __restrict__ bits,
                            const float* __restrict__ W_h, const float* __restrict__ b_h,
                            const float* __restrict__ W_o,
                            __bf16* __restrict__ Bt1, float* __restrict__ biasp,
                            __bf16* __restrict__ Bt2,
                            const float* __restrict__ X, __bf16* __restrict__ Xb,
                            float* __restrict__ zeros) {
    const int b = blockIdx.x, t = threadIdx.x;
    if (b < 1024) {                               // prepack + zeroing
        int idx = b * 256 + t;                    // [0, 262144)
        {
            int n = idx >> 9, k = idx & 511;
            int h = n >> 7, f = n & 127;
            Bt1[idx] = (__bf16)W_h[(size_t)h * 512 * 128 + k * 128 + f];
        }
        if (idx < 64 * 512) {
            int n = idx >> 9, k = idx & 511;
            Bt2[idx] = (__bf16)W_o[k * 64 + n];
        }
        if (idx < 512) biasp[idx] = b_h[idx];
        if (idx < (10 * NN) / 4)                  // zero s1h/s2h/s1o/s2o (40960 f32)
            *(f32x4*)(zeros + (size_t)idx * 4) = (f32x4){0.f, 0.f, 0.f, 0.f};
    } else if (b < 3072) {                        // cast X -> bf16
        int i = (b - 1024) * 256 + t;             // [0, 524288) x4 floats
        f32x4 v = *(const f32x4*)(X + (size_t)i * 4);
        bf16x4 o;
#pragma unroll
        for (int q = 0; q < 4; q++) o[q] = (__bf16)v[q];
        *(bf16x4*)(Xb + (size_t)i * 4) = o;
    } else {                                      // pack_adj, grid-strided
        int wave = (b - 3072) * 4 + (t >> 6);     // [0, 16384)
        int lane = t & 63;
        int g0 = wave * 16;                       // 16 consecutive 64-col groups
        for (int it = 0; it < 16; it++) {
            int gw = g0 + it;
            int v = adj[(size_t)gw * 64 + lane];
            unsigned long long m = __ballot(v > 0);
            if (lane == 0) bits[gw] = m;
        }
    }
}

// ---------------- fused bf16 MFMA GEMM ----------------
// Ht[col][row] = bf16( (A @ Bt^T)[row][col] + bias[col] )   (transposed store)
// s1[head][row] += sum_col h*a1[col]*LOG2E, s2 likewise (pre-scaled for exp2;
// lrelu is positively homogeneous so the scale commutes through it exactly).
__global__ __launch_bounds__(256) void gemm_fused_kernel(
    const __bf16* __restrict__ A, const __bf16* __restrict__ Bt,
    const float* __restrict__ bias,
    const float* __restrict__ a1, const float* __restrict__ a2,
    __bf16* __restrict__ Ht, float* __restrict__ s1, float* __restrict__ s2,
    int M, int N, int K)
{
    __shared__ __attribute__((aligned(16))) __bf16 As[2][64 * 64];
    __shared__ __attribute__((aligned(16))) __bf16 Bs[2][64 * 64];
    const int tid = threadIdx.x, w = tid >> 6, l = tid & 63, o = l >> 4, rl = l & 15;
    const int bm = blockIdx.y * 64, bn = blockIdx.x * 64;
    f32x4 acc[4] = {};
    stage_g(A + (size_t)bm * K, K, &As[0][0], tid);
    stage_g(Bt + (size_t)bn * K, K, &Bs[0][0], tid);
    const int KB = K / 64;
    for (int kb = 0; kb < KB; kb++) {
        int b = kb & 1;
        __syncthreads();
        if (kb + 1 < KB) {
            stage_g(A + (size_t)bm * K + (kb + 1) * 64, K, &As[b ^ 1][0], tid);
            stage_g(Bt + (size_t)bn * K + (kb + 1) * 64, K, &Bs[b ^ 1][0], tid);
        }
#pragma unroll
        for (int kt = 0; kt < 2; kt++) {
            int ra = w * 16 + rl;
            int cg = kt * 4 + o;
            bf16x8 af = *(const bf16x8*)(&As[b][(ra * 8 + (cg ^ (ra & 7))) * 8]);
#pragma unroll
            for (int nt = 0; nt < 4; nt++) {
                int rb = nt * 16 + rl;
                bf16x8 bfr = *(const bf16x8*)(&Bs[b][(rb * 8 + (cg ^ (rb & 7))) * 8]);
                acc[nt] = __builtin_amdgcn_mfma_f32_16x16x32_bf16(af, bfr, acc[nt], 0, 0, 0);
            }
        }
    }
    // epilogue: bias, transposed bf16 store, s1/s2 row-dot partials
    const int head = bn >> 7;
    const int row_base = bm + w * 16 + o * 4;
    float p1[4] = {0.f, 0.f, 0.f, 0.f}, p2[4] = {0.f, 0.f, 0.f, 0.f};
#pragma unroll
    for (int nt = 0; nt < 4; nt++) {
        int col = bn + nt * 16 + rl;
        float bv = bias[col];
        float a1v = a1[col] * LOG2E, a2v = a2[col] * LOG2E;
        bf16x4 hv;
#pragma unroll
        for (int r4 = 0; r4 < 4; r4++) {
            float h = acc[nt][r4] + bv;
            hv[r4] = (__bf16)h;
            p1[r4] += h * a1v;
            p2[r4] += h * a2v;
        }
        *(bf16x4*)(Ht + (size_t)col * M + row_base) = hv;
    }
#pragma unroll
    for (int r4 = 0; r4 < 4; r4++)
#pragma unroll
        for (int off = 1; off < 16; off <<= 1) {
            p1[r4] += __shfl_xor(p1[r4], off, 64);
            p2[r4] += __shfl_xor(p2[r4], off, 64);
        }
    if (rl == 0)
#pragma unroll
        for (int r4 = 0; r4 < 4; r4++) {
            atomicAdd(&s1[(size_t)head * M + row_base + r4], p1[r4]);
            atomicAdd(&s2[(size_t)head * M + row_base + r4], p2[r4]);
        }
}

// ---------------- MFMA attention, SELF-CONSUME, j-split partials ----------------
// R5 winning structure: wave w keeps its own P fragments and computes m-tile w
// across ALL n-tiles; one barrier/iter; no plds.
// Round-6: mrow REMOVED (softmax is shift-invariant; |e| <= ~15 here vs f32
// exp2 range +-126, so mrow=0 is numerically safe and exact) -> no s2max
// dependency, no smax kernels, two fewer dispatches.
template<int FH, int JSPLIT>
__global__ __launch_bounds__(256, 4) void attn_kernel(
    const __bf16* __restrict__ Htg,               // [heads*FH][NN]
    const unsigned long long* __restrict__ adj_bits,
    const float* __restrict__ s1_all, const float* __restrict__ s2_all,
    const float* __restrict__ ab_all,
    __bf16* __restrict__ accp,                    // [JSPLIT][NN][ldo]
    float* __restrict__ lg,                       // [heads*JSPLIT][NN]
    int ldo)
{
    constexpr int NJT = NN / 64 / JSPLIT;         // 16 (layer1) / 4 (layer2)
    constexpr int NTL = FH / 16;                  // n-tiles per wave (8 or 4)
    const int head = blockIdx.y;
    const int js   = blockIdx.z;
    const int row0 = blockIdx.x * 64;
    const int jt0  = js * NJT;
    const int tid = threadIdx.x;
    const int w = tid >> 6, l = tid & 63, o = l >> 4, rl = l & 15;
    const int myrow = row0 + w * 16 + rl;         // this wave's m-tile rows

    __shared__ __attribute__((aligned(16))) __bf16 hbuf[2][FH * 64];

    const float* s2 = s2_all + (size_t)head * NN;
    const __bf16* hg = Htg + (size_t)head * FH * NN;
    // s1/s2 already carry the LOG2E scale from the GEMM epilogue; ab scaled here.
    const float s1r = s1_all[(size_t)head * NN + myrow] + ab_all[head] * LOG2E;
    const float u0 = s1r;                         // e = max(s+u0, fma(.2,s,v0))
    const float v0 = 0.2f * s1r;
    float lacc = 0.f;                             // per-lane partial; reduced at end
    f32x4 acc[NTL] = {};                          // m-tile w, all n-tiles

    // ---- flat prefetch state (named regs only -> guaranteed VGPRs)
    unsigned long long aw;
    f32x4 sA0, sB0, sA1, sB1;                     // s2[jt*64 + kt*32 + o*8 ..+8)

    auto PLOAD = [&](int jt) {
        aw = adj_bits[(size_t)myrow * 64 + jt];
        const float* sp = s2 + jt * 64 + o * 8;
        sA0 = *(const f32x4*)(sp);       sB0 = *(const f32x4*)(sp + 4);
        sA1 = *(const f32x4*)(sp + 32);  sB1 = *(const f32x4*)(sp + 36);
    };
    auto PMATH = [&](bf16x8& f0, bf16x8& f1) {
        float ps = 0.f;
        {
            unsigned int mb = (unsigned int)(aw >> (o * 8)) & 0xFFu;      // kt=0
#pragma unroll
            for (int q = 0; q < 8; q++) {
                float s = (q < 4) ? sA0[q] : sB0[q - 4];
                float t = fmaxf(s + u0, fmaf(0.2f, s, v0));
                t = ((mb >> q) & 1u) ? t : -1.0e20f;
                float p = EXP2(t);
                f0[q] = (__bf16)p; ps += p;
            }
        }
        {
            unsigned int mb = (unsigned int)(aw >> (32 + o * 8)) & 0xFFu; // kt=1
#pragma unroll
            for (int q = 0; q < 8; q++) {
                float s = (q < 4) ? sA1[q] : sB1[q - 4];
                float t = fmaxf(s + u0, fmaf(0.2f, s, v0));
                t = ((mb >> q) & 1u) ? t : -1.0e20f;
                float p = EXP2(t);
                f1[q] = (__bf16)p; ps += p;
            }
        }
        lacc += ps;
    };

    stage_tile<FH>(hg + (size_t)jt0 * 64, &hbuf[0][0], tid);
    PLOAD(jt0);

    for (int jl = 0; jl < NJT; jl++) {
        const int b = jl & 1;
        const int jt = jt0 + jl;
        // ONE barrier: hbuf[b] DMA drained (vmcnt 0); hbuf[b^1] free to overwrite
        __syncthreads();
        if (jl + 1 < NJT)
            stage_tile<FH>(hg + (size_t)(jt + 1) * 64, &hbuf[b ^ 1][0], tid);
        // produce this tile's P fragments from regs prefetched last iteration
        bf16x8 fc0, fc1;
        PMATH(fc0, fc1);
        if (jl + 1 < NJT) PLOAD(jt + 1);          // covered by MFMA cluster below
        // consume: own m-tile, ALL n-tiles (wave-local, no cross-wave sync)
        __builtin_amdgcn_s_setprio(1);
#pragma unroll
        for (int ntl = 0; ntl < NTL; ntl++) {
            int f = ntl * 16 + rl;
            int s0 = o ^ (rl & 7);                // kt=0 slot
            int s1 = (4 + o) ^ (rl & 7);          // kt=1 slot
            bf16x8 b0 = *(const bf16x8*)(&hbuf[b][(f * 8 + s0) * 8]);
            bf16x8 b1 = *(const bf16x8*)(&hbuf[b][(f * 8 + s1) * 8]);
            acc[ntl] = __builtin_amdgcn_mfma_f32_16x16x32_bf16(fc0, b0, acc[ntl], 0, 0, 0);
            acc[ntl] = __builtin_amdgcn_mfma_f32_16x16x32_bf16(fc1, b1, acc[ntl], 0, 0, 0);
        }
        __builtin_amdgcn_s_setprio(0);
    }
    // ---- epilogue: cross-lane lacc reduce (deferred from loop) ----
    lacc += __shfl_xor(lacc, 16, 64);
    lacc += __shfl_xor(lacc, 32, 64);
    if (l < 16) lg[((size_t)head * JSPLIT + js) * NN + row0 + w * 16 + l] = lacc;
#pragma unroll
    for (int ntl = 0; ntl < NTL; ntl++)
#pragma unroll
        for (int r4 = 0; r4 < 4; r4++) {
            int grow = row0 + w * 16 + o * 4 + r4;
            int gcol = head * FH + ntl * 16 + rl;
            accp[((size_t)js * NN + grow) * ldo + gcol] = (__bf16)acc[ntl][r4];
        }
}

// ---------------- combine layer-1 partials: normalize + elu -> bf16 [N][512] ----------------
__global__ void combine1_kernel(const __bf16* __restrict__ accp, const float* __restrict__ lg,
                                __bf16* __restrict__ outb) {
    int gid = blockIdx.x * 256 + threadIdx.x;        // N * 128
    int row = gid >> 7, c4 = (gid & 127) * 4;
    int head = c4 >> 7;
    float lsum = 0.f;
#pragma unroll
    for (int js = 0; js < 4; js++) lsum += lg[((size_t)head * 4 + js) * NN + row];
    float inv = lsum > 0.f ? 1.f / lsum : 0.f;
    float v[4] = {0.f, 0.f, 0.f, 0.f};
#pragma unroll
    for (int js = 0; js < 4; js++) {
        bf16x4 t = *(const bf16x4*)(accp + ((size_t)js * NN + row) * 512 + c4);
#pragma unroll
        for (int q = 0; q < 4; q++) v[q] += (float)t[q];
    }
    bf16x4 ob;
#pragma unroll
    for (int q = 0; q < 4; q++) {
        float x = v[q] * inv;
        x = x > 0.f ? x : __expf(x) - 1.f;
        ob[q] = (__bf16)x;
    }
    *(bf16x4*)(outb + (size_t)row * 512 + c4) = ob;
}

// ---------------- combine layer-2 partials + elu + log_softmax -> out ----------------
__global__ void combine2_kernel(const __bf16* __restrict__ accp, const float* __restrict__ lg,
                                float* __restrict__ out) {
    int row = (blockIdx.x * 256 + threadIdx.x) >> 6;
    int lane = threadIdx.x & 63;
    if (row >= NN) return;
    float lsum = 0.f, v = 0.f;
#pragma unroll
    for (int js = 0; js < 16; js++) {
        lsum += lg[(size_t)js * NN + row];
        v += (float)accp[((size_t)js * NN + row) * 64 + lane];
    }
    float inv = lsum > 0.f ? 1.f / lsum : 0.f;
    v *= inv;
    v = v > 0.f ? v : __expf(v) - 1.f;
    float m = v;
#pragma unroll
    for (int off = 1; off < 64; off <<= 1) m = fmaxf(m, __shfl_xor(m, off, 64));
    float ex = __expf(v - m);
    float s = ex;
#pragma unroll
    for (int off = 1; off < 64; off <<= 1) s += __shfl_xor(s, off, 64);
    out[(size_t)row * 64 + lane] = v - m - __logf(s);
}

extern "C" void kernel_launch(void* const* d_in, const int* in_sizes, int n_in,
                              void* d_out, int out_size, void* d_ws, size_t ws_size,
                              hipStream_t stream) {
    const float* X    = (const float*)d_in[0];
    const int*   adj  = (const int*)d_in[1];
    const float* W_h  = (const float*)d_in[2];
    const float* b_h  = (const float*)d_in[3];
    const float* a1_h = (const float*)d_in[4];
    const float* a2_h = (const float*)d_in[5];
    const float* ab_h = (const float*)d_in[6];
    const float* W_o  = (const float*)d_in[7];
    const float* b_o  = (const float*)d_in[8];
    const float* a1_o = (const float*)d_in[9];
    const float* a2_o = (const float*)d_in[10];
    const float* ab_o = (const float*)d_in[11];
    float* out = (float*)d_out;

    char* ws = (char*)d_ws;
    auto alloc = [&](size_t bytes) {
        char* p = ws; ws += (bytes + 255) & ~(size_t)255; return p;
    };
    unsigned long long* adj_bits = (unsigned long long*)alloc((size_t)NN * 64 * 8); // 2 MB
    __bf16* Bt1    = (__bf16*)alloc((size_t)512 * 512 * 2);     // 512 KB
    float*  biasp  = (float*)alloc(512 * 4);
    __bf16* Bt2    = (__bf16*)alloc((size_t)64 * 512 * 2);      // 64 KB
    __bf16* Xb     = (__bf16*)alloc((size_t)NN * 512 * 2);      // 4 MB
    float*  s1h    = (float*)alloc((size_t)4 * NN * 4);         // |-- contiguous,
    float*  s2h    = (float*)alloc((size_t)4 * NN * 4);         // |   zeroed by prep
    float*  s1o    = (float*)alloc((size_t)NN * 4);             // |   (160 KB)
    float*  s2o    = (float*)alloc((size_t)NN * 4);             // |
    __bf16* Htg    = (__bf16*)alloc((size_t)512 * NN * 2);      // 4 MB
    __bf16* accp1  = (__bf16*)alloc((size_t)4 * NN * 512 * 2);  // 16 MB
    float*  lg1    = (float*)alloc((size_t)16 * NN * 4);        // 256 KB
    __bf16* outhb  = (__bf16*)alloc((size_t)NN * 512 * 2);      // 4 MB
    __bf16* Ht2    = (__bf16*)alloc((size_t)64 * NN * 2);       // 512 KB
    __bf16* accp2  = (__bf16*)alloc((size_t)16 * NN * 64 * 2);  // 8 MB
    float*  lg2    = (float*)alloc((size_t)16 * NN * 4);        // 256 KB  (~40 MB)

    // 1. fused prep: adj->bits, weight prepack, X cast, s1/s2 zeroing (1 dispatch)
    prep_kernel<<<7168, 256, 0, stream>>>(adj, adj_bits, W_h, b_h, W_o,
                                          Bt1, biasp, Bt2, X, Xb, s1h);
    // 2. layer-1 GEMM fused: Htg (transposed bf16) + s1h/s2h atomics (LOG2E-scaled)
    gemm_fused_kernel<<<dim3(8, 64), 256, 0, stream>>>(
        Xb, Bt1, biasp, a1_h, a2_h, Htg, s1h, s2h, NN, 512, 512);
    // 3. attention layer 1 partials (4 heads x 4 j-splits)
    attn_kernel<128, 4><<<dim3(NN / 64, 4, 4), 256, 0, stream>>>(
        Htg, adj_bits, s1h, s2h, ab_h, accp1, lg1, 512);
    // 4. combine -> elu -> bf16 concat features [N][512]
    combine1_kernel<<<(NN * 128) / 256, 256, 0, stream>>>(accp1, lg1, outhb);
    // 5. layer-2 GEMM fused: Ht2 (transposed bf16) + s1o/s2o atomics (LOG2E-scaled)
    gemm_fused_kernel<<<dim3(1, 64), 256, 0, stream>>>(
        outhb, Bt2, b_o, a1_o, a2_o, Ht2, s1o, s2o, NN, 64, 512);
    // 6. attention layer 2 partials (16 j-splits)
    attn_kernel<64, 16><<<dim3(NN / 64, 1, 16), 256, 0, stream>>>(
        Ht2, adj_bits, s1o, s2o, ab_o, accp2, lg2, 64);
    // 7. combine + elu + log_softmax -> out
    combine2_kernel<<<(NN * 64) / 256, 256, 0, stream>>>(accp2, lg2, out);
}

// Round 7
// 204.135 us; speedup vs baseline: 1.3241x; 1.0251x over previous
//
#include <hip/hip_runtime.h>
#include <math.h>

#define NN 4096   // nodes
#define LOG2E 1.44269504088896340736f

using f32x4  = __attribute__((ext_vector_type(4))) float;
using bf16x4 = __attribute__((ext_vector_type(4))) __bf16;
using bf16x8 = __attribute__((ext_vector_type(8))) __bf16;

// exp2 in one v_exp_f32 (inputs are pre-scaled by log2e)
#if __has_builtin(__builtin_amdgcn_exp2f)
#define EXP2(x) __builtin_amdgcn_exp2f(x)
#else
#define EXP2(x) __expf((x) * 0.6931471805599453f)
#endif

// counted-vmcnt barrier (T4): keep next-tile DMA in flight across the barrier.
// vmcnt(4) = wait until the current tile's 4 global_load_lds (A:2 + B:2) retired,
// leaving the prefetched tile's 4 outstanding. NEVER drain to 0 mid-loop.
#define WAITVM4_BARRIER asm volatile("s_waitcnt vmcnt(4)\ns_barrier" ::: "memory")
#define WAITVM0_BARRIER asm volatile("s_waitcnt vmcnt(0)\ns_barrier" ::: "memory")

// ---------------- async global->LDS staging (16B, XOR-swizzled chunks) ----------------
// Row f of 64 bf16 = 8 chunks of 8; LDS slot s of row f holds global chunk s^(f&7).
template<int FH>
__device__ __forceinline__ void stage_tile(const __bf16* __restrict__ hgp,
                                           __bf16* dst, int tid) {
#pragma unroll
    for (int it = 0; it < FH / 32; it++) {
        int c = tid + it * 256;
        int f = c >> 3, sl = c & 7;
        int g = sl ^ (f & 7);
        __builtin_amdgcn_global_load_lds(
            (const __attribute__((address_space(1))) void*)(hgp + (size_t)f * NN + g * 8),
            (__attribute__((address_space(3))) void*)(dst + (size_t)c * 8), 16, 0, 0);
    }
}

__device__ __forceinline__ void stage_g(const __bf16* __restrict__ base, int ldk,
                                        __bf16* dst, int tid) {
#pragma unroll
    for (int it = 0; it < 2; it++) {
        int c = tid + it * 256;
        int f = c >> 3, sl = c & 7;
        int g = sl ^ (f & 7);
        __builtin_amdgcn_global_load_lds(
            (const __attribute__((address_space(1))) void*)(base + (size_t)f * ldk + g * 8),
            (__attribute__((address_space(3))) void*)(dst + (size_t)c * 8), 16, 0, 0);
    }
}

// ---------------- fused prep: memset + prepack + cast + pack_adj in ONE dispatch ----
__global__ void prep_kernel(const int* __restrict__ adj, unsigned long long* __restrict__ bits,
                            const float* __restrict__ W_h, const float* __restrict__ b_h,
                            const float* __restrict__ W_o,
                            __bf16* __restrict__ Bt1, float* __restrict__ biasp,
                            __bf16* __restrict__ Bt2,
                            const float* __restrict__ X, __bf16* __restrict__ Xb,
                            float* __restrict__ zeros) {
    const int b = blockIdx.x, t = threadIdx.x;
    if (b < 1024) {                               // prepack + zeroing
        int idx = b * 256 + t;                    // [0, 262144)
        {
            int n = idx >> 9, k = idx & 511;
            int h = n >> 7, f = n & 127;
            Bt1[idx] = (__bf16)W_h[(size_t)h * 512 * 128 + k * 128 + f];
        }
        if (idx < 64 * 512) {
            int n = idx >> 9, k = idx & 511;
            Bt2[idx] = (__bf16)W_o[k * 64 + n];
        }
        if (idx < 512) biasp[idx] = b_h[idx];
        if (idx < (10 * NN) / 4)                  // zero s1h/s2h/s1o/s2o (40960 f32)
            *(f32x4*)(zeros + (size_t)idx * 4) = (f32x4){0.f, 0.f, 0.f, 0.f};
    } else if (b < 3072) {                        // cast X -> bf16
        int i = (b - 1024) * 256 + t;             // [0, 524288) x4 floats
        f32x4 v = *(const f32x4*)(X + (size_t)i * 4);
        bf16x4 o;
#pragma unroll
        for (int q = 0; q < 4; q++) o[q] = (__bf16)v[q];
        *(bf16x4*)(Xb + (size_t)i * 4) = o;
    } else {                                      // pack_adj, grid-strided
        int wave = (b - 3072) * 4 + (t >> 6);     // [0, 16384)
        int lane = t & 63;
        int g0 = wave * 16;                       // 16 consecutive 64-col groups
        for (int it = 0; it < 16; it++) {
            int gw = g0 + it;
            int v = adj[(size_t)gw * 64 + lane];
            unsigned long long m = __ballot(v > 0);
            if (lane == 0) bits[gw] = m;
        }
    }
}

// ---------------- fused bf16 MFMA GEMM (triple-buffer + counted vmcnt) ----------------
// Ht[col][row] = bf16( (A @ Bt^T)[row][col] + bias[col] )   (transposed store)
// s1[head][row] += sum_col h*a1[col]*LOG2E, s2 likewise (pre-scaled for exp2).
// Round-7: 2-deep DMA pipeline. The old __syncthreads drained vmcnt(0) on a
// prefetch that had only ~500 cy of compute cover (HBM latency ~900 cy) ->
// ~400 cy exposed per K-step. Now: 3 LDS buffers, stage(kb+2) issued AFTER
// compute(kb) (so every wave is past compute(kb-1), the last reader of that
// buffer), and a counted s_waitcnt vmcnt(4) + raw s_barrier at the loop top
// retires exactly the current tile while the next stays in flight.
__global__ __launch_bounds__(256) void gemm_fused_kernel(
    const __bf16* __restrict__ A, const __bf16* __restrict__ Bt,
    const float* __restrict__ bias,
    const float* __restrict__ a1, const float* __restrict__ a2,
    __bf16* __restrict__ Ht, float* __restrict__ s1, float* __restrict__ s2,
    int M, int N, int K)
{
    __shared__ __attribute__((aligned(16))) __bf16 As[3][64 * 64];
    __shared__ __attribute__((aligned(16))) __bf16 Bs[3][64 * 64];
    const int tid = threadIdx.x, w = tid >> 6, l = tid & 63, o = l >> 4, rl = l & 15;
    const int bm = blockIdx.y * 64, bn = blockIdx.x * 64;
    f32x4 acc[4] = {};
    // prologue: stage tiles 0 and 1 (8 DMA instructions in flight)
    stage_g(A + (size_t)bm * K, K, &As[0][0], tid);
    stage_g(Bt + (size_t)bn * K, K, &Bs[0][0], tid);
    stage_g(A + (size_t)bm * K + 64, K, &As[1][0], tid);
    stage_g(Bt + (size_t)bn * K + 64, K, &Bs[1][0], tid);
    const int KB = K / 64;                        // 8
    int b = 0;
    for (int kb = 0; kb < KB; kb++) {
        if (kb + 1 < KB) { WAITVM4_BARRIER; }     // tile kb landed; kb+1 in flight
        else             { WAITVM0_BARRIER; }     // last tile: full drain
#pragma unroll
        for (int kt = 0; kt < 2; kt++) {
            int ra = w * 16 + rl;
            int cg = kt * 4 + o;
            bf16x8 af = *(const bf16x8*)(&As[b][(ra * 8 + (cg ^ (ra & 7))) * 8]);
#pragma unroll
            for (int nt = 0; nt < 4; nt++) {
                int rb = nt * 16 + rl;
                bf16x8 bfr = *(const bf16x8*)(&Bs[b][(rb * 8 + (cg ^ (rb & 7))) * 8]);
                acc[nt] = __builtin_amdgcn_mfma_f32_16x16x32_bf16(af, bfr, acc[nt], 0, 0, 0);
            }
        }
        // stage kb+2 into the buffer last read at compute(kb-1): all waves are
        // past the top-of-kb barrier, hence done with compute(kb-1). Safe.
        if (kb + 2 < KB) {
            int b2 = b + 2; if (b2 >= 3) b2 -= 3;
            stage_g(A + (size_t)bm * K + (kb + 2) * 64, K, &As[b2][0], tid);
            stage_g(Bt + (size_t)bn * K + (kb + 2) * 64, K, &Bs[b2][0], tid);
        }
        if (++b == 3) b = 0;
    }
    // epilogue: bias, transposed bf16 store, s1/s2 row-dot partials
    const int head = bn >> 7;
    const int row_base = bm + w * 16 + o * 4;
    float p1[4] = {0.f, 0.f, 0.f, 0.f}, p2[4] = {0.f, 0.f, 0.f, 0.f};
#pragma unroll
    for (int nt = 0; nt < 4; nt++) {
        int col = bn + nt * 16 + rl;
        float bv = bias[col];
        float a1v = a1[col] * LOG2E, a2v = a2[col] * LOG2E;
        bf16x4 hv;
#pragma unroll
        for (int r4 = 0; r4 < 4; r4++) {
            float h = acc[nt][r4] + bv;
            hv[r4] = (__bf16)h;
            p1[r4] += h * a1v;
            p2[r4] += h * a2v;
        }
        *(bf16x4*)(Ht + (size_t)col * M + row_base) = hv;
    }
#pragma unroll
    for (int r4 = 0; r4 < 4; r4++)
#pragma unroll
        for (int off = 1; off < 16; off <<= 1) {
            p1[r4] += __shfl_xor(p1[r4], off, 64);
            p2[r4] += __shfl_xor(p2[r4], off, 64);
        }
    if (rl == 0)
#pragma unroll
        for (int r4 = 0; r4 < 4; r4++) {
            atomicAdd(&s1[(size_t)head * M + row_base + r4], p1[r4]);
            atomicAdd(&s2[(size_t)head * M + row_base + r4], p2[r4]);
        }
}

// ---------------- MFMA attention, SELF-CONSUME + in-wave PMATH/MFMA overlap ----------
// R5 structure (wave w owns m-tile w across ALL n-tiles, one barrier/iter).
// Round-7: PMATH for tile jl+1 computed BETWEEN setprio(1) and the MFMA cluster
// consuming tile jl's fragments (fc). fn/fc are independent register streams,
// so the scheduler interleaves the exp2 VALU chain with the MFMAs and the
// ds_read shadows — removing PMATH (~260 cy) from the per-iter critical path.
// mrow=0 (shift-invariance; |e| <= ~15 vs exp2 range +-126).
template<int FH, int JSPLIT>
__global__ __launch_bounds__(256, 4) void attn_kernel(
    const __bf16* __restrict__ Htg,               // [heads*FH][NN]
    const unsigned long long* __restrict__ adj_bits,
    const float* __restrict__ s1_all, const float* __restrict__ s2_all,
    const float* __restrict__ ab_all,
    __bf16* __restrict__ accp,                    // [JSPLIT][NN][ldo]
    float* __restrict__ lg,                       // [heads*JSPLIT][NN]
    int ldo)
{
    constexpr int NJT = NN / 64 / JSPLIT;         // 16 (layer1) / 4 (layer2)
    constexpr int NTL = FH / 16;                  // n-tiles per wave (8 or 4)
    const int head = blockIdx.y;
    const int js   = blockIdx.z;
    const int row0 = blockIdx.x * 64;
    const int jt0  = js * NJT;
    const int tid = threadIdx.x;
    const int w = tid >> 6, l = tid & 63, o = l >> 4, rl = l & 15;
    const int myrow = row0 + w * 16 + rl;         // this wave's m-tile rows

    __shared__ __attribute__((aligned(16))) __bf16 hbuf[2][FH * 64];

    const float* s2 = s2_all + (size_t)head * NN;
    const __bf16* hg = Htg + (size_t)head * FH * NN;
    const float s1r = s1_all[(size_t)head * NN + myrow] + ab_all[head] * LOG2E;
    const float u0 = s1r;                         // e = max(s+u0, fma(.2,s,v0))
    const float v0 = 0.2f * s1r;
    float lacc = 0.f;                             // per-lane partial; reduced at end
    f32x4 acc[NTL] = {};                          // m-tile w, all n-tiles

    // ---- flat prefetch state (named regs only -> guaranteed VGPRs)
    unsigned long long aw;
    f32x4 sA0, sB0, sA1, sB1;                     // s2[jt*64 + kt*32 + o*8 ..+8)

    auto PLOAD = [&](int jt) {
        aw = adj_bits[(size_t)myrow * 64 + jt];
        const float* sp = s2 + jt * 64 + o * 8;
        sA0 = *(const f32x4*)(sp);       sB0 = *(const f32x4*)(sp + 4);
        sA1 = *(const f32x4*)(sp + 32);  sB1 = *(const f32x4*)(sp + 36);
    };
    auto PMATH = [&](bf16x8& f0, bf16x8& f1) {
        float ps = 0.f;
        {
            unsigned int mb = (unsigned int)(aw >> (o * 8)) & 0xFFu;      // kt=0
#pragma unroll
            for (int q = 0; q < 8; q++) {
                float s = (q < 4) ? sA0[q] : sB0[q - 4];
                float t = fmaxf(s + u0, fmaf(0.2f, s, v0));
                t = ((mb >> q) & 1u) ? t : -1.0e20f;
                float p = EXP2(t);
                f0[q] = (__bf16)p; ps += p;
            }
        }
        {
            unsigned int mb = (unsigned int)(aw >> (32 + o * 8)) & 0xFFu; // kt=1
#pragma unroll
            for (int q = 0; q < 8; q++) {
                float s = (q < 4) ? sA1[q] : sB1[q - 4];
                float t = fmaxf(s + u0, fmaf(0.2f, s, v0));
                t = ((mb >> q) & 1u) ? t : -1.0e20f;
                float p = EXP2(t);
                f1[q] = (__bf16)p; ps += p;
            }
        }
        lacc += ps;
    };

    stage_tile<FH>(hg + (size_t)jt0 * 64, &hbuf[0][0], tid);
    PLOAD(jt0);
    bf16x8 fc0, fc1, fn0, fn1;
    PMATH(fc0, fc1);                              // tile 0 fragments (overlaps DMA)
    if (NJT > 1) PLOAD(jt0 + 1);

    for (int jl = 0; jl < NJT; jl++) {
        const int b = jl & 1;
        const int jt = jt0 + jl;
        // ONE barrier: hbuf[b] DMA drained (vmcnt 0); hbuf[b^1] free to overwrite
        __syncthreads();
        if (jl + 1 < NJT)
            stage_tile<FH>(hg + (size_t)(jt + 1) * 64, &hbuf[b ^ 1][0], tid);
        __builtin_amdgcn_s_setprio(1);
        // produce NEXT tile's fragments (independent of fc / hbuf[b]) — the
        // scheduler interleaves this VALU chain with the MFMA cluster below.
        if (jl + 1 < NJT) PMATH(fn0, fn1);
        if (jl + 2 < NJT) PLOAD(jt + 2);
        // consume: own m-tile, ALL n-tiles (wave-local, no cross-wave sync)
#pragma unroll
        for (int ntl = 0; ntl < NTL; ntl++) {
            int f = ntl * 16 + rl;
            int s0 = o ^ (rl & 7);                // kt=0 slot
            int s1 = (4 + o) ^ (rl & 7);          // kt=1 slot
            bf16x8 b0 = *(const bf16x8*)(&hbuf[b][(f * 8 + s0) * 8]);
            bf16x8 b1 = *(const bf16x8*)(&hbuf[b][(f * 8 + s1) * 8]);
            acc[ntl] = __builtin_amdgcn_mfma_f32_16x16x32_bf16(fc0, b0, acc[ntl], 0, 0, 0);
            acc[ntl] = __builtin_amdgcn_mfma_f32_16x16x32_bf16(fc1, b1, acc[ntl], 0, 0, 0);
        }
        __builtin_amdgcn_s_setprio(0);
        if (jl + 1 < NJT) { fc0 = fn0; fc1 = fn1; }
    }
    // ---- epilogue: cross-lane lacc reduce (deferred from loop) ----
    lacc += __shfl_xor(lacc, 16, 64);
    lacc += __shfl_xor(lacc, 32, 64);
    if (l < 16) lg[((size_t)head * JSPLIT + js) * NN + row0 + w * 16 + l] = lacc;
#pragma unroll
    for (int ntl = 0; ntl < NTL; ntl++)
#pragma unroll
        for (int r4 = 0; r4 < 4; r4++) {
            int grow = row0 + w * 16 + o * 4 + r4;
            int gcol = head * FH + ntl * 16 + rl;
            accp[((size_t)js * NN + grow) * ldo + gcol] = (__bf16)acc[ntl][r4];
        }
}

// ---------------- combine layer-1 partials: normalize + elu -> bf16 [N][512] ----------------
__global__ void combine1_kernel(const __bf16* __restrict__ accp, const float* __restrict__ lg,
                                __bf16* __restrict__ outb) {
    int gid = blockIdx.x * 256 + threadIdx.x;        // N * 128
    int row = gid >> 7, c4 = (gid & 127) * 4;
    int head = c4 >> 7;
    float lsum = 0.f;
#pragma unroll
    for (int js = 0; js < 4; js++) lsum += lg[((size_t)head * 4 + js) * NN + row];
    float inv = lsum > 0.f ? 1.f / lsum : 0.f;
    float v[4] = {0.f, 0.f, 0.f, 0.f};
#pragma unroll
    for (int js = 0; js < 4; js++) {
        bf16x4 t = *(const bf16x4*)(accp + ((size_t)js * NN + row) * 512 + c4);
#pragma unroll
        for (int q = 0; q < 4; q++) v[q] += (float)t[q];
    }
    bf16x4 ob;
#pragma unroll
    for (int q = 0; q < 4; q++) {
        float x = v[q] * inv;
        x = x > 0.f ? x : __expf(x) - 1.f;
        ob[q] = (__bf16)x;
    }
    *(bf16x4*)(outb + (size_t)row * 512 + c4) = ob;
}

// ---------------- combine layer-2 partials + elu + log_softmax -> out ----------------
__global__ void combine2_kernel(const __bf16* __restrict__ accp, const float* __restrict__ lg,
                                float* __restrict__ out) {
    int row = (blockIdx.x * 256 + threadIdx.x) >> 6;
    int lane = threadIdx.x & 63;
    if (row >= NN) return;
    float lsum = 0.f, v = 0.f;
#pragma unroll
    for (int js = 0; js < 16; js++) {
        lsum += lg[(size_t)js * NN + row];
        v += (float)accp[((size_t)js * NN + row) * 64 + lane];
    }
    float inv = lsum > 0.f ? 1.f / lsum : 0.f;
    v *= inv;
    v = v > 0.f ? v : __expf(v) - 1.f;
    float m = v;
#pragma unroll
    for (int off = 1; off < 64; off <<= 1) m = fmaxf(m, __shfl_xor(m, off, 64));
    float ex = __expf(v - m);
    float s = ex;
#pragma unroll
    for (int off = 1; off < 64; off <<= 1) s += __shfl_xor(s, off, 64);
    out[(size_t)row * 64 + lane] = v - m - __logf(s);
}

extern "C" void kernel_launch(void* const* d_in, const int* in_sizes, int n_in,
                              void* d_out, int out_size, void* d_ws, size_t ws_size,
                              hipStream_t stream) {
    const float* X    = (const float*)d_in[0];
    const int*   adj  = (const int*)d_in[1];
    const float* W_h  = (const float*)d_in[2];
    const float* b_h  = (const float*)d_in[3];
    const float* a1_h = (const float*)d_in[4];
    const float* a2_h = (const float*)d_in[5];
    const float* ab_h = (const float*)d_in[6];
    const float* W_o  = (const float*)d_in[7];
    const float* b_o  = (const float*)d_in[8];
    const float* a1_o = (const float*)d_in[9];
    const float* a2_o = (const float*)d_in[10];
    const float* ab_o = (const float*)d_in[11];
    float* out = (float*)d_out;

    char* ws = (char*)d_ws;
    auto alloc = [&](size_t bytes) {
        char* p = ws; ws += (bytes + 255) & ~(size_t)255; return p;
    };
    unsigned long long* adj_bits = (unsigned long long*)alloc((size_t)NN * 64 * 8); // 2 MB
    __bf16* Bt1    = (__bf16*)alloc((size_t)512 * 512 * 2);     // 512 KB
    float*  biasp  = (float*)alloc(512 * 4);
    __bf16* Bt2    = (__bf16*)alloc((size_t)64 * 512 * 2);      // 64 KB
    __bf16* Xb     = (__bf16*)alloc((size_t)NN * 512 * 2);      // 4 MB
    float*  s1h    = (float*)alloc((size_t)4 * NN * 4);         // |-- contiguous,
    float*  s2h    = (float*)alloc((size_t)4 * NN * 4);         // |   zeroed by prep
    float*  s1o    = (float*)alloc((size_t)NN * 4);             // |   (160 KB)
    float*  s2o    = (float*)alloc((size_t)NN * 4);             // |
    __bf16* Htg    = (__bf16*)alloc((size_t)512 * NN * 2);      // 4 MB
    __bf16* accp1  = (__bf16*)alloc((size_t)4 * NN * 512 * 2);  // 16 MB
    float*  lg1    = (float*)alloc((size_t)16 * NN * 4);        // 256 KB
    __bf16* outhb  = (__bf16*)alloc((size_t)NN * 512 * 2);      // 4 MB
    __bf16* Ht2    = (__bf16*)alloc((size_t)64 * NN * 2);      // 512 KB
    __bf16* accp2  = (__bf16*)alloc((size_t)16 * NN * 64 * 2);  // 8 MB
    float*  lg2    = (float*)alloc((size_t)16 * NN * 4);        // 256 KB  (~40 MB)

    // 1. fused prep: adj->bits, weight prepack, X cast, s1/s2 zeroing (1 dispatch)
    prep_kernel<<<7168, 256, 0, stream>>>(adj, adj_bits, W_h, b_h, W_o,
                                          Bt1, biasp, Bt2, X, Xb, s1h);
    // 2. layer-1 GEMM fused: Htg (transposed bf16) + s1h/s2h atomics (LOG2E-scaled)
    gemm_fused_kernel<<<dim3(8, 64), 256, 0, stream>>>(
        Xb, Bt1, biasp, a1_h, a2_h, Htg, s1h, s2h, NN, 512, 512);
    // 3. attention layer 1 partials (4 heads x 4 j-splits)
    attn_kernel<128, 4><<<dim3(NN / 64, 4, 4), 256, 0, stream>>>(
        Htg, adj_bits, s1h, s2h, ab_h, accp1, lg1, 512);
    // 4. combine -> elu -> bf16 concat features [N][512]
    combine1_kernel<<<(NN * 128) / 256, 256, 0, stream>>>(accp1, lg1, outhb);
    // 5. layer-2 GEMM fused: Ht2 (transposed bf16) + s1o/s2o atomics (LOG2E-scaled)
    gemm_fused_kernel<<<dim3(1, 64), 256, 0, stream>>>(
        outhb, Bt2, b_o, a1_o, a2_o, Ht2, s1o, s2o, NN, 64, 512);
    // 6. attention layer 2 partials (16 j-splits)
    attn_kernel<64, 16><<<dim3(NN / 64, 1, 16), 256, 0, stream>>>(
        Ht2, adj_bits, s1o, s2o, ab_o, accp2, lg2, 64);
    // 7. combine + elu + log_softmax -> out
    combine2_kernel<<<(NN * 64) / 256, 256, 0, stream>>>(accp2, lg2, out);
}